// Round 1
// baseline (10689.906 us; speedup 1.0000x reference)
//
#include <hip/hip_runtime.h>
#include <math.h>

// Problem constants (from reference)
constexpr int cV = 32000, cE = 768, cL = 4, cC = 256, cTL = 1024;
constexpr int cED = 3072, cS0 = 1536, cPIN = 2304;
constexpr int cB = 2, cT = 2048, cN = 8, cNCH = 16, cMR = 16384; // cMR = 16*1024 rows

// ---------------------------------------------------------------- reductions
__device__ inline float blockReduceSum256(float v, float* sbuf) {
    #pragma unroll
    for (int m = 1; m < 64; m <<= 1) v += __shfl_xor(v, m, 64);
    int lane = threadIdx.x & 63, w = threadIdx.x >> 6;
    if (lane == 0) sbuf[w] = v;
    __syncthreads();
    return sbuf[0] + sbuf[1] + sbuf[2] + sbuf[3];
}

// ---------------------------------------------------------------- embed + token-normalize
__global__ __launch_bounds__(256) void embed_k(const int* __restrict__ ids,
                                               const float* __restrict__ wte,
                                               float* __restrict__ x,
                                               float* __restrict__ xnt) {
    __shared__ float sb[4];
    int tok = blockIdx.x;
    const float* src = wte + (size_t)ids[tok] * cE;
    int t = threadIdx.x;
    float v0 = src[t], v1 = src[t + 256], v2 = src[t + 512];
    float tot = blockReduceSum256(v0 * v0 + v1 * v1 + v2 * v2, sb);
    float inv = 1.0f / (sqrtf(tot) + 1e-8f);
    size_t o = (size_t)tok * cE + t;
    x[o] = v0; x[o + 256] = v1; x[o + 512] = v2;
    xnt[o] = v0 * inv; xnt[o + 256] = v1 * inv; xnt[o + 512] = v2 * inv;
}

// ---------------------------------------------------------------- rmsnorm (row of 768)
__global__ __launch_bounds__(256) void rmsnorm_k(const float* __restrict__ in,
                                                 const float* __restrict__ w,
                                                 float* __restrict__ out) {
    __shared__ float sb[4];
    size_t row = blockIdx.x;
    const float* src = in + row * cE;
    int t = threadIdx.x;
    float v0 = src[t], v1 = src[t + 256], v2 = src[t + 512];
    float tot = blockReduceSum256(v0 * v0 + v1 * v1 + v2 * v2, sb);
    float s = 1.0f / sqrtf(tot * (1.0f / cE) + 1e-10f);
    out[row * cE + t]       = v0 * s * w[t];
    out[row * cE + t + 256] = v1 * s * w[t + 256];
    out[row * cE + t + 512] = v2 * s * w[t + 512];
}

// ---------------------------------------------------------------- inverse row norm of a (= xp[:, :768])
__global__ __launch_bounds__(256) void invna_k(const float* __restrict__ xp,
                                               float* __restrict__ invna) {
    __shared__ float sb[4];
    size_t row = blockIdx.x;
    const float* src = xp + row * (size_t)cED;
    int t = threadIdx.x;
    float v0 = src[t], v1 = src[t + 256], v2 = src[t + 512];
    float tot = blockReduceSum256(v0 * v0 + v1 * v1 + v2 * v2, sb);
    if (t == 0) invna[row] = 1.0f / sqrtf(tot + 1e-8f);
}

// ---------------------------------------------------------------- final row extract + rmsnorm(lnf)
__global__ __launch_bounds__(256) void final_k(const float* __restrict__ h,
                                               const float* __restrict__ lnf,
                                               float* __restrict__ finn) {
    __shared__ float sb[4];
    int tok = blockIdx.x;                 // 0..4095 = b*T + t
    int b = tok >> 11, tt = tok & 2047;
    int i = tt >> 8, c = tt & 255;
    size_t row = (size_t)(b * cN + i) * cTL + (cTL - cC) + c;
    const float* src = h + row * cE;
    int t = threadIdx.x;
    float v0 = src[t], v1 = src[t + 256], v2 = src[t + 512];
    float tot = blockReduceSum256(v0 * v0 + v1 * v1 + v2 * v2, sb);
    float s = 1.0f / sqrtf(tot * (1.0f / cE) + 1e-10f);
    size_t o = (size_t)tok * cE + t;
    finn[o]       = v0 * s * lnf[t];
    finn[o + 256] = v1 * s * lnf[t + 256];
    finn[o + 512] = v2 * s * lnf[t + 512];
}

// ---------------------------------------------------------------- pair scores: sum_c max_k (xn_i[c] . xn_j[k])
// grid: (4 ctiles, 56 pairs). Block 256 = 16x16, microtile 4x4 over 64c x 64k.
__global__ __launch_bounds__(256) void pair_scores_k(const float* __restrict__ xnt,
                                                     float* __restrict__ partial) {
    __shared__ float As[16][64];
    __shared__ float Bs[16][64];
    __shared__ float srow[64];
    int ct = blockIdx.x;
    int p  = blockIdx.y;
    int b = p / 28, pp = p % 28;
    int i = 1; while (pp >= i) { pp -= i; i++; }
    int j = pp;
    const float* Abase  = xnt + ((size_t)(b * cT) + i * cC + ct * 64) * cE;
    const float* Bbase0 = xnt + ((size_t)(b * cT) + j * cC) * cE;
    int tid = threadIdx.x, tx = tid & 15, ty = tid >> 4;
    int srl = tid >> 2, skc = (tid & 3) << 2;
    float rmax[4] = {-1e30f, -1e30f, -1e30f, -1e30f};
    for (int nt = 0; nt < 4; nt++) {
        const float* Bbase = Bbase0 + (size_t)nt * 64 * cE;
        float acc[4][4] = {};
        for (int k0 = 0; k0 < cE; k0 += 16) {
            float4 va = *(const float4*)(Abase + (size_t)srl * cE + k0 + skc);
            As[skc + 0][srl] = va.x; As[skc + 1][srl] = va.y; As[skc + 2][srl] = va.z; As[skc + 3][srl] = va.w;
            float4 vb = *(const float4*)(Bbase + (size_t)srl * cE + k0 + skc);
            Bs[skc + 0][srl] = vb.x; Bs[skc + 1][srl] = vb.y; Bs[skc + 2][srl] = vb.z; Bs[skc + 3][srl] = vb.w;
            __syncthreads();
            #pragma unroll
            for (int k = 0; k < 16; k++) {
                float4 a  = *(float4*)&As[k][ty << 2];
                float4 bb = *(float4*)&Bs[k][tx << 2];
                float am[4] = {a.x, a.y, a.z, a.w};
                float bn[4] = {bb.x, bb.y, bb.z, bb.w};
                #pragma unroll
                for (int r = 0; r < 4; r++)
                    #pragma unroll
                    for (int q = 0; q < 4; q++)
                        acc[r][q] = fmaf(am[r], bn[q], acc[r][q]);
            }
            __syncthreads();
        }
        #pragma unroll
        for (int r = 0; r < 4; r++) {
            float mx = fmaxf(fmaxf(acc[r][0], acc[r][1]), fmaxf(acc[r][2], acc[r][3]));
            #pragma unroll
            for (int d = 1; d < 16; d <<= 1) mx = fmaxf(mx, __shfl_xor(mx, d, 64));
            rmax[r] = fmaxf(rmax[r], mx);
        }
    }
    if (tx == 0) {
        #pragma unroll
        for (int r = 0; r < 4; r++) srow[(ty << 2) + r] = rmax[r];
    }
    __syncthreads();
    if (tid == 0) {
        float s = 0.f;
        for (int r = 0; r < 64; r++) s += srow[r];   // fixed order -> deterministic
        partial[p * 4 + ct] = s;
    }
}

// ---------------------------------------------------------------- combine partials + top-k + sort + weights
__global__ void score_topk_k(const float* __restrict__ partial,
                             int* __restrict__ sidx, float* __restrict__ sw) {
    __shared__ float sc[2][8][8];
    int t = threadIdx.x;
    if (t < 56) {
        int b = t / 28, pp = t % 28;
        int i = 1; while (pp >= i) { pp -= i; i++; }
        int j = pp;
        sc[b][i][j] = partial[t * 4 + 0] + partial[t * 4 + 1] + partial[t * 4 + 2] + partial[t * 4 + 3];
    }
    __syncthreads();
    if (t < 16) {
        int b = t >> 3, i = t & 7;
        int nsel = i < 3 ? i : 3;
        if (nsel > 0) {
            float loc[7];
            for (int j2 = 0; j2 < i; j2++) loc[j2] = sc[b][i][j2];
            int idxs[3]; float vals[3];
            for (int s = 0; s < nsel; s++) {        // selection: strict > keeps lowest index on tie (top_k)
                int am = 0; float mv = loc[0];
                for (int j2 = 1; j2 < i; j2++) if (loc[j2] > mv) { mv = loc[j2]; am = j2; }
                idxs[s] = am; vals[s] = mv; loc[am] = -1e30f;
            }
            for (int a = 0; a < nsel; a++)          // sort by index ascending
                for (int c2 = a + 1; c2 < nsel; c2++)
                    if (idxs[c2] < idxs[a]) {
                        int ti = idxs[a]; idxs[a] = idxs[c2]; idxs[c2] = ti;
                        float tv = vals[a]; vals[a] = vals[c2]; vals[c2] = tv;
                    }
            float den = vals[0] + 1e-8f;
            for (int s = 0; s < nsel; s++) {
                sidx[(b * 8 + i) * 3 + s] = idxs[s];
                sw[(b * 8 + i) * 3 + s]   = vals[s] / den;
            }
        }
    }
}

// ---------------------------------------------------------------- assemble extended context h (16,1024,768)
__global__ __launch_bounds__(192) void build_k(const float* __restrict__ x,
                                               const int* __restrict__ sidx,
                                               const float* __restrict__ sw,
                                               float* __restrict__ h) {
    int m = blockIdx.x, r = blockIdx.y;
    int b = m >> 3, i = m & 7;
    int nsel = i < 3 ? i : 3;
    int pad = cTL - (nsel + 1) * cC;
    int pos = r - pad;
    float4 val = make_float4(0.f, 0.f, 0.f, 0.f);
    if (pos >= 0) {
        if (pos < nsel * cC) {
            int s = pos >> 8;
            int jj = sidx[(b * 8 + i) * 3 + s];
            float wg = sw[(b * 8 + i) * 3 + s];
            const float4* src = (const float4*)(x + ((size_t)(b * cT) + jj * cC + (pos & 255)) * cE);
            float4 v = src[threadIdx.x];
            val = make_float4(v.x * wg, v.y * wg, v.z * wg, v.w * wg);
        } else {
            int c = pos - nsel * cC;
            const float4* src = (const float4*)(x + ((size_t)(b * cT) + i * cC + c) * cE);
            val = src[threadIdx.x];
        }
    }
    ((float4*)(h + ((size_t)m * cTL + r) * cE))[threadIdx.x] = val;
}

// ---------------------------------------------------------------- xp b-slot *= anew  (builds a*b in place)
__global__ __launch_bounds__(192) void bmul_k(float* __restrict__ xp,
                                              const float* __restrict__ anew) {
    size_t row = blockIdx.x;
    float4* bp = (float4*)(xp + row * cED + cE);
    const float4* ap = (const float4*)(anew + row * cE);
    float4 bv = bp[threadIdx.x], av = ap[threadIdx.x];
    bp[threadIdx.x] = make_float4(bv.x * av.x, bv.y * av.y, bv.z * av.z, bv.w * av.w);
}

// ---------------------------------------------------------------- generic fp32 GEMM, 128x128x16 tile, 8x8 microtile
// C[m,n] = sum_k A[m,k] * B'[k,n];  BNT: B'[k,n] = B[n*ldb+k] (NT), else B'[k,n] = B[k*ldb+n] (NN)
enum { EPI_PLAIN = 0, EPI_RELU_SQ = 1, EPI_CS = 2, EPI_ADD_H = 3 };

template <int EPI, bool BNT>
__global__ __launch_bounds__(256) void gemm_k(
        const float* __restrict__ A, int lda, long sA,
        const float* __restrict__ Bm, int ldb, long sB,
        float* __restrict__ C, int ldc, long sC,
        int K,
        const float* __restrict__ bias,
        const float* __restrict__ invna,
        const float* __restrict__ sp) {
    const int n0 = blockIdx.x << 7, m0 = blockIdx.y << 7, z = blockIdx.z;
    const int tid = threadIdx.x, tx = tid & 15, ty = tid >> 4;
    float* Cb = C + (size_t)z * sC;

    if constexpr (EPI == EPI_CS) {
        if (n0 > m0 + 127) {           // strictly upper triangle: all zeros
            float4 zv = make_float4(0.f, 0.f, 0.f, 0.f);
            #pragma unroll
            for (int r2 = 0; r2 < 8; r2++) {
                float4* cp = (float4*)(Cb + (size_t)(m0 + (ty << 3) + r2) * ldc + n0 + (tx << 3));
                cp[0] = zv; cp[1] = zv;
            }
            return;
        }
    }

    const float* Ab = A + (size_t)z * sA;
    const float* Bb = Bm + (size_t)z * sB;

    __shared__ float As[16][128];
    __shared__ float Bs[16][128];

    float acc[8][8];
    #pragma unroll
    for (int i2 = 0; i2 < 8; i2++)
        #pragma unroll
        for (int j2 = 0; j2 < 8; j2++) acc[i2][j2] = 0.f;

    for (int k0 = 0; k0 < K; k0 += 16) {
        #pragma unroll
        for (int q = 0; q < 2; q++) {
            int l = tid + (q << 8);
            int row = l >> 2, kc = (l & 3) << 2;
            float4 v = *(const float4*)(Ab + (size_t)(m0 + row) * lda + (k0 + kc));
            As[kc + 0][row] = v.x; As[kc + 1][row] = v.y; As[kc + 2][row] = v.z; As[kc + 3][row] = v.w;
        }
        if constexpr (BNT) {
            #pragma unroll
            for (int q = 0; q < 2; q++) {
                int l = tid + (q << 8);
                int row = l >> 2, kc = (l & 3) << 2;
                float4 v = *(const float4*)(Bb + (size_t)(n0 + row) * ldb + (k0 + kc));
                Bs[kc + 0][row] = v.x; Bs[kc + 1][row] = v.y; Bs[kc + 2][row] = v.z; Bs[kc + 3][row] = v.w;
            }
        } else {
            #pragma unroll
            for (int q = 0; q < 2; q++) {
                int l = tid + (q << 8);
                int kk = l >> 5, c = (l & 31) << 2;
                *(float4*)&Bs[kk][c] = *(const float4*)(Bb + (size_t)(k0 + kk) * ldb + (n0 + c));
            }
        }
        __syncthreads();
        #pragma unroll
        for (int k = 0; k < 16; k++) {
            float4 a0 = *(float4*)&As[k][ty << 3];
            float4 a1 = *(float4*)&As[k][(ty << 3) + 4];
            float4 b0 = *(float4*)&Bs[k][tx << 3];
            float4 b1 = *(float4*)&Bs[k][(tx << 3) + 4];
            float am[8] = {a0.x, a0.y, a0.z, a0.w, a1.x, a1.y, a1.z, a1.w};
            float bn[8] = {b0.x, b0.y, b0.z, b0.w, b1.x, b1.y, b1.z, b1.w};
            #pragma unroll
            for (int i2 = 0; i2 < 8; i2++)
                #pragma unroll
                for (int j2 = 0; j2 < 8; j2++)
                    acc[i2][j2] = fmaf(am[i2], bn[j2], acc[i2][j2]);
        }
        __syncthreads();
    }

    #pragma unroll
    for (int i2 = 0; i2 < 8; i2++) {
        int gm = m0 + (ty << 3) + i2;
        float* crow = Cb + (size_t)gm * ldc + n0 + (tx << 3);
        float vout[8];
        if constexpr (EPI == EPI_CS) {
            float im = invna[z * 1024 + gm];
            const float* spr = sp + (size_t)gm * 1024;
            #pragma unroll
            for (int j2 = 0; j2 < 8; j2++) {
                int gn = n0 + (tx << 3) + j2;
                vout[j2] = (gn <= gm) ? acc[i2][j2] * im * invna[z * 1024 + gn] * spr[gn] : 0.f;
            }
        } else if constexpr (EPI == EPI_RELU_SQ) {
            #pragma unroll
            for (int j2 = 0; j2 < 8; j2++) {
                float tv = acc[i2][j2] + bias[n0 + (tx << 3) + j2];
                tv = fmaxf(tv, 0.f);
                vout[j2] = tv * tv;
            }
        } else if constexpr (EPI == EPI_ADD_H) {
            #pragma unroll
            for (int j2 = 0; j2 < 8; j2++)
                vout[j2] = crow[j2] + acc[i2][j2] + bias[n0 + (tx << 3) + j2];
        } else {
            #pragma unroll
            for (int j2 = 0; j2 < 8; j2++) vout[j2] = acc[i2][j2];
        }
        ((float4*)crow)[0] = make_float4(vout[0], vout[1], vout[2], vout[3]);
        ((float4*)crow)[1] = make_float4(vout[4], vout[5], vout[6], vout[7]);
    }
}

// ---------------------------------------------------------------- launch
extern "C" void kernel_launch(void* const* d_in, const int* in_sizes, int n_in,
                              void* d_out, int out_size, void* d_ws, size_t ws_size,
                              hipStream_t stream) {
    const int*   ids  = (const int*)d_in[0];
    const float* wte  = (const float*)d_in[1];
    const float* rmsw = (const float*)d_in[2];
    const float* enrw = (const float*)d_in[3];
    const float* enrb = (const float*)d_in[4];
    const float* sp   = (const float*)d_in[5];
    const float* fusw = (const float*)d_in[6];
    const float* fusb = (const float*)d_in[7];
    const float* lnfw = (const float*)d_in[8];
    float* out = (float*)d_out;

    float* ws   = (float*)d_ws;
    float* x    = ws;                    // 3,145,728 (also reused as finn)
    float* xnt  = x   + 3145728;         // 3,145,728
    float* h    = xnt + 3145728;         // 12,582,912
    float* xn   = h   + 12582912;        // 12,582,912 (also anew)
    float* xp   = xn  + 12582912;        // 50,331,648
    float* cs   = xp  + 50331648;        // 16,777,216
    float* invn = cs  + 16777216;        // 16,384
    float* part = invn + 16384;          // 256
    float* swv  = part + 256;            // 64
    int*   sidx = (int*)(swv + 64);      // 64 ints
    float* finn = x;

    // 1. embed + token normalize
    embed_k<<<cB * cT, 256, 0, stream>>>(ids, wte, x, xnt);
    // 2. retrieval scores + top-k + assembly
    pair_scores_k<<<dim3(4, 56), 256, 0, stream>>>(xnt, part);
    score_topk_k<<<1, 64, 0, stream>>>(part, sidx, swv);
    build_k<<<dim3(cNCH, cTL), 192, 0, stream>>>(x, sidx, swv, h);

    // 3. layers
    for (int l = 0; l < cL; l++) {
        rmsnorm_k<<<cMR, 256, 0, stream>>>(h, rmsw + (size_t)l * cE, xn);
        gemm_k<EPI_RELU_SQ, true><<<dim3(cED / 128, cMR / 128, 1), 256, 0, stream>>>(
            xn, cE, 0, enrw + (size_t)l * cED * cE, cE, 0, xp, cED, 0, cE,
            enrb + (size_t)l * cED, nullptr, nullptr);
        invna_k<<<cMR, 256, 0, stream>>>(xp, invn);
        gemm_k<EPI_CS, true><<<dim3(8, 8, cNCH), 256, 0, stream>>>(
            xp, cED, (long)cTL * cED, xp, cED, (long)cTL * cED,
            cs, cTL, (long)cTL * cTL, cE,
            nullptr, invn, sp + (size_t)l * cTL * cTL);
        gemm_k<EPI_PLAIN, false><<<dim3(cE / 128, 8, cNCH), 256, 0, stream>>>(
            cs, cTL, (long)cTL * cTL, xp, cED, (long)cTL * cED,
            xn, cE, (long)cTL * cE, cTL,
            nullptr, nullptr, nullptr);
        bmul_k<<<cMR, 192, 0, stream>>>(xp, xn);
        gemm_k<EPI_ADD_H, true><<<dim3(cE / 128, cMR / 128, 1), 256, 0, stream>>>(
            xp + cE, cED, 0, fusw + (size_t)l * cE * cPIN, cPIN, 0, h, cE, 0, cPIN,
            fusb + (size_t)l * cE, nullptr, nullptr);
    }

    // 4. final norm + logits
    final_k<<<cB * cT, 256, 0, stream>>>(h, lnfw, finn);
    gemm_k<EPI_PLAIN, true><<<dim3(cV / 128, (cB * cT) / 128, 1), 256, 0, stream>>>(
        finn, cE, 0, wte, cE, 0, out, cV, 0, cE,
        nullptr, nullptr, nullptr);
}

// Round 2
// 2119.864 us; speedup vs baseline: 5.0427x; 5.0427x over previous
//
#include <hip/hip_runtime.h>
#include <math.h>

typedef unsigned short u16;
typedef __attribute__((ext_vector_type(8))) short bf16x8;
typedef __attribute__((ext_vector_type(4))) float f32x4;

// Problem constants
constexpr int cV = 32000, cE = 768, cL = 4, cC = 256, cTL = 1024;
constexpr int cED = 3072, cPIN = 2304;
constexpr int cB = 2, cT = 2048, cN = 8, cNCH = 16, cMR = 16384;

// ---------------------------------------------------------------- bf16 helpers
__device__ inline float bf2f(u16 u) {
    union { uint32_t i; float f; } v; v.i = ((uint32_t)u) << 16; return v.f;
}
__device__ inline u16 f2bf(float f) {
    union { float f; uint32_t u; } v; v.f = f;
    uint32_t r = v.u + 0x7FFF + ((v.u >> 16) & 1);
    return (u16)(r >> 16);
}

// async global->LDS, 16B per lane; LDS dest is wave-uniform base + lane*16
#define GLOAD16(gp, lp) __builtin_amdgcn_global_load_lds( \
    (const __attribute__((address_space(1))) void*)(gp), \
    (__attribute__((address_space(3))) void*)(lp), 16, 0, 0)

// ---------------------------------------------------------------- reductions
__device__ inline float blockReduceSum256(float v, float* sbuf) {
    #pragma unroll
    for (int m = 1; m < 64; m <<= 1) v += __shfl_xor(v, m, 64);
    int lane = threadIdx.x & 63, w = threadIdx.x >> 6;
    if (lane == 0) sbuf[w] = v;
    __syncthreads();
    return sbuf[0] + sbuf[1] + sbuf[2] + sbuf[3];
}

// ---------------------------------------------------------------- fp32 -> bf16 bulk convert
__global__ __launch_bounds__(256) void cvt_k(const float* __restrict__ in,
                                             u16* __restrict__ out, long n) {
    long i = ((long)blockIdx.x * 256 + threadIdx.x) * 4;
    if (i >= n) return;
    float4 v = *(const float4*)(in + i);
    uint32_t lo = f2bf(v.x) | ((uint32_t)f2bf(v.y) << 16);
    uint32_t hi = f2bf(v.z) | ((uint32_t)f2bf(v.w) << 16);
    *(uint2*)(out + i) = make_uint2(lo, hi);
}

// ---------------------------------------------------------------- embed + token-normalize (fp32, feeds topk)
__global__ __launch_bounds__(256) void embed_k(const int* __restrict__ ids,
                                               const float* __restrict__ wte,
                                               float* __restrict__ x,
                                               float* __restrict__ xnt) {
    __shared__ float sb[4];
    int tok = blockIdx.x;
    const float* src = wte + (size_t)ids[tok] * cE;
    int t = threadIdx.x;
    float v0 = src[t], v1 = src[t + 256], v2 = src[t + 512];
    float tot = blockReduceSum256(v0 * v0 + v1 * v1 + v2 * v2, sb);
    float inv = 1.0f / (sqrtf(tot) + 1e-8f);
    size_t o = (size_t)tok * cE + t;
    x[o] = v0; x[o + 256] = v1; x[o + 512] = v2;
    xnt[o] = v0 * inv; xnt[o + 256] = v1 * inv; xnt[o + 512] = v2 * inv;
}

// ---------------------------------------------------------------- rmsnorm -> bf16
__global__ __launch_bounds__(256) void rmsnorm_bf_k(const float* __restrict__ in,
                                                    const float* __restrict__ w,
                                                    u16* __restrict__ out) {
    __shared__ float sb[4];
    size_t row = blockIdx.x;
    const float* src = in + row * cE;
    int t = threadIdx.x;
    float v0 = src[t], v1 = src[t + 256], v2 = src[t + 512];
    float tot = blockReduceSum256(v0 * v0 + v1 * v1 + v2 * v2, sb);
    float s = 1.0f / sqrtf(tot * (1.0f / cE) + 1e-10f);
    out[row * cE + t]       = f2bf(v0 * s * w[t]);
    out[row * cE + t + 256] = f2bf(v1 * s * w[t + 256]);
    out[row * cE + t + 512] = f2bf(v2 * s * w[t + 512]);
}

// ---------------------------------------------------------------- inverse row norm of a (bf16 input)
__global__ __launch_bounds__(256) void invna_bf_k(const u16* __restrict__ a,
                                                  float* __restrict__ invna) {
    __shared__ float sb[4];
    size_t row = blockIdx.x;
    const u16* src = a + row * cE;
    int t = threadIdx.x;
    float v0 = bf2f(src[t]), v1 = bf2f(src[t + 256]), v2 = bf2f(src[t + 512]);
    float tot = blockReduceSum256(v0 * v0 + v1 * v1 + v2 * v2, sb);
    if (t == 0) invna[row] = 1.0f / sqrtf(tot + 1e-8f);
}

// ---------------------------------------------------------------- final row extract + rmsnorm(lnf) -> bf16
__global__ __launch_bounds__(256) void final_bf_k(const float* __restrict__ h,
                                                  const float* __restrict__ lnf,
                                                  u16* __restrict__ finn) {
    __shared__ float sb[4];
    int tok = blockIdx.x;
    int b = tok >> 11, tt = tok & 2047;
    int i = tt >> 8, c = tt & 255;
    size_t row = (size_t)(b * cN + i) * cTL + (cTL - cC) + c;
    const float* src = h + row * cE;
    int t = threadIdx.x;
    float v0 = src[t], v1 = src[t + 256], v2 = src[t + 512];
    float tot = blockReduceSum256(v0 * v0 + v1 * v1 + v2 * v2, sb);
    float s = 1.0f / sqrtf(tot * (1.0f / cE) + 1e-10f);
    size_t o = (size_t)tok * cE + t;
    finn[o]       = f2bf(v0 * s * lnf[t]);
    finn[o + 256] = f2bf(v1 * s * lnf[t + 256]);
    finn[o + 512] = f2bf(v2 * s * lnf[t + 512]);
}

// ---------------------------------------------------------------- pair scores (fp32, deterministic; unchanged)
__global__ __launch_bounds__(256) void pair_scores_k(const float* __restrict__ xnt,
                                                     float* __restrict__ partial) {
    __shared__ float As[16][64];
    __shared__ float Bs[16][64];
    __shared__ float srow[64];
    int ct = blockIdx.x;
    int p  = blockIdx.y;
    int b = p / 28, pp = p % 28;
    int i = 1; while (pp >= i) { pp -= i; i++; }
    int j = pp;
    const float* Abase  = xnt + ((size_t)(b * cT) + i * cC + ct * 64) * cE;
    const float* Bbase0 = xnt + ((size_t)(b * cT) + j * cC) * cE;
    int tid = threadIdx.x, tx = tid & 15, ty = tid >> 4;
    int srl = tid >> 2, skc = (tid & 3) << 2;
    float rmax[4] = {-1e30f, -1e30f, -1e30f, -1e30f};
    for (int nt = 0; nt < 4; nt++) {
        const float* Bbase = Bbase0 + (size_t)nt * 64 * cE;
        float acc[4][4] = {};
        for (int k0 = 0; k0 < cE; k0 += 16) {
            float4 va = *(const float4*)(Abase + (size_t)srl * cE + k0 + skc);
            As[skc + 0][srl] = va.x; As[skc + 1][srl] = va.y; As[skc + 2][srl] = va.z; As[skc + 3][srl] = va.w;
            float4 vb = *(const float4*)(Bbase + (size_t)srl * cE + k0 + skc);
            Bs[skc + 0][srl] = vb.x; Bs[skc + 1][srl] = vb.y; Bs[skc + 2][srl] = vb.z; Bs[skc + 3][srl] = vb.w;
            __syncthreads();
            #pragma unroll
            for (int k = 0; k < 16; k++) {
                float4 a  = *(float4*)&As[k][ty << 2];
                float4 bb = *(float4*)&Bs[k][tx << 2];
                float am[4] = {a.x, a.y, a.z, a.w};
                float bn[4] = {bb.x, bb.y, bb.z, bb.w};
                #pragma unroll
                for (int r = 0; r < 4; r++)
                    #pragma unroll
                    for (int q = 0; q < 4; q++)
                        acc[r][q] = fmaf(am[r], bn[q], acc[r][q]);
            }
            __syncthreads();
        }
        #pragma unroll
        for (int r = 0; r < 4; r++) {
            float mx = fmaxf(fmaxf(acc[r][0], acc[r][1]), fmaxf(acc[r][2], acc[r][3]));
            #pragma unroll
            for (int d = 1; d < 16; d <<= 1) mx = fmaxf(mx, __shfl_xor(mx, d, 64));
            rmax[r] = fmaxf(rmax[r], mx);
        }
    }
    if (tx == 0) {
        #pragma unroll
        for (int r = 0; r < 4; r++) srow[(ty << 2) + r] = rmax[r];
    }
    __syncthreads();
    if (tid == 0) {
        float s = 0.f;
        for (int r = 0; r < 64; r++) s += srow[r];
        partial[p * 4 + ct] = s;
    }
}

// ---------------------------------------------------------------- top-k + sort + weights (unchanged)
__global__ void score_topk_k(const float* __restrict__ partial,
                             int* __restrict__ sidx, float* __restrict__ sw) {
    __shared__ float sc[2][8][8];
    int t = threadIdx.x;
    if (t < 56) {
        int b = t / 28, pp = t % 28;
        int i = 1; while (pp >= i) { pp -= i; i++; }
        int j = pp;
        sc[b][i][j] = partial[t * 4 + 0] + partial[t * 4 + 1] + partial[t * 4 + 2] + partial[t * 4 + 3];
    }
    __syncthreads();
    if (t < 16) {
        int b = t >> 3, i = t & 7;
        int nsel = i < 3 ? i : 3;
        if (nsel > 0) {
            float loc[7];
            for (int j2 = 0; j2 < i; j2++) loc[j2] = sc[b][i][j2];
            int idxs[3]; float vals[3];
            for (int s = 0; s < nsel; s++) {
                int am = 0; float mv = loc[0];
                for (int j2 = 1; j2 < i; j2++) if (loc[j2] > mv) { mv = loc[j2]; am = j2; }
                idxs[s] = am; vals[s] = mv; loc[am] = -1e30f;
            }
            for (int a = 0; a < nsel; a++)
                for (int c2 = a + 1; c2 < nsel; c2++)
                    if (idxs[c2] < idxs[a]) {
                        int ti = idxs[a]; idxs[a] = idxs[c2]; idxs[c2] = ti;
                        float tv = vals[a]; vals[a] = vals[c2]; vals[c2] = tv;
                    }
            float den = vals[0] + 1e-8f;
            for (int s = 0; s < nsel; s++) {
                sidx[(b * 8 + i) * 3 + s] = idxs[s];
                sw[(b * 8 + i) * 3 + s]   = vals[s] / den;
            }
        }
    }
}

// ---------------------------------------------------------------- assemble extended context h (fp32)
__global__ __launch_bounds__(192) void build_k(const float* __restrict__ x,
                                               const int* __restrict__ sidx,
                                               const float* __restrict__ sw,
                                               float* __restrict__ h) {
    int m = blockIdx.x, r = blockIdx.y;
    int b = m >> 3, i = m & 7;
    int nsel = i < 3 ? i : 3;
    int pad = cTL - (nsel + 1) * cC;
    int pos = r - pad;
    float4 val = make_float4(0.f, 0.f, 0.f, 0.f);
    if (pos >= 0) {
        if (pos < nsel * cC) {
            int s = pos >> 8;
            int jj = sidx[(b * 8 + i) * 3 + s];
            float wg = sw[(b * 8 + i) * 3 + s];
            const float4* src = (const float4*)(x + ((size_t)(b * cT) + jj * cC + (pos & 255)) * cE);
            float4 v = src[threadIdx.x];
            val = make_float4(v.x * wg, v.y * wg, v.z * wg, v.w * wg);
        } else {
            int c = pos - nsel * cC;
            const float4* src = (const float4*)(x + ((size_t)(b * cT) + i * cC + c) * cE);
            val = src[threadIdx.x];
        }
    }
    ((float4*)(h + ((size_t)m * cTL + r) * cE))[threadIdx.x] = val;
}

// ---------------------------------------------------------------- transpose(a_newT) * fi[:, :768] -> fi[:, :768]
__global__ __launch_bounds__(256) void tmul_k(const u16* __restrict__ anT,
                                              u16* __restrict__ fi) {
    __shared__ u16 tile[64][65];
    int c0 = blockIdx.x << 6, j0 = blockIdx.y << 6, z = blockIdx.z;
    const u16* src = anT + (size_t)z * (cE * cTL);
    int t = threadIdx.x;
    #pragma unroll
    for (int it = 0; it < 16; it++) {
        int id = t + (it << 8);
        int r = id >> 6, c = id & 63;
        tile[r][c] = src[(size_t)(j0 + r) * cTL + c0 + c];
    }
    __syncthreads();
    #pragma unroll
    for (int it = 0; it < 16; it++) {
        int id = t + (it << 8);
        int cm = id >> 6, jj = id & 63;
        size_t o = (size_t)(z * cTL + c0 + cm) * cPIN + j0 + jj;
        fi[o] = f2bf(bf2f(tile[jj][cm]) * bf2f(fi[o]));
    }
}

// ---------------------------------------------------------------- bf16 MFMA GEMM (m97 structure)
// NT: C[m,n] = sum_k A[m*lda+k] * B[n*ldb+k]; 128x128 tile, BK=32, 4 waves, 16x16x32 MFMA
enum { GE_F32 = 0, GE_RELU = 1, GE_CS = 2, GE_ADDH = 3, GE_BF16 = 4 };

template <int EPI>
__global__ __launch_bounds__(256) void gemm_bt(
        const u16* __restrict__ A, int lda, size_t sA,
        const u16* __restrict__ B, int ldb, size_t sB,
        void* __restrict__ Cv, int ldc, size_t sC, int K,
        const float* __restrict__ bias,
        const float* __restrict__ invn,
        const float* __restrict__ sp,
        u16* __restrict__ p0, u16* __restrict__ p1, u16* __restrict__ p2)
{
    const int n0 = blockIdx.x << 7, m0 = blockIdx.y << 7, z = blockIdx.z;
    const int tid = threadIdx.x, lane = tid & 63, w = tid >> 6;
    const int wr = w >> 1, wc = w & 1;

    if constexpr (EPI == GE_CS) {
        if (n0 > m0) {  // strictly-upper 128x128 block: all zeros
            u16* Cb = (u16*)Cv + (size_t)z * sC;
            uint4 zv = make_uint4(0u, 0u, 0u, 0u);
            #pragma unroll
            for (int it = 0; it < 8; it++) {
                int id = tid + (it << 8);
                int r = id >> 4, c = id & 15;
                *(uint4*)(Cb + (size_t)(m0 + r) * ldc + n0 + (c << 3)) = zv;
            }
            return;
        }
    }

    __shared__ __align__(16) u16 As[128 * 32];
    __shared__ __align__(16) u16 Bs[128 * 32];

    const u16* Ab = A + (size_t)z * sA + (size_t)m0 * lda;
    const u16* Bb = B + (size_t)z * sB + (size_t)n0 * ldb;

    // staging: wave w covers rows [w*32, w*32+32) in two 1KB chunks (16 rows each)
    const int srow = (w << 5) + (lane >> 2);
    const int skof = (lane & 3) << 3;
    const u16* ga0 = Ab + (size_t)srow * lda + skof;
    const u16* gb0 = Bb + (size_t)srow * ldb + skof;
    u16* la0 = As + (w << 10);   // ushort offset = w*1024 (byte w*2048)
    u16* lb0 = Bs + (w << 10);

    f32x4 acc[4][4];
    #pragma unroll
    for (int m = 0; m < 4; m++)
        #pragma unroll
        for (int n = 0; n < 4; n++)
            acc[m][n] = (f32x4){0.f, 0.f, 0.f, 0.f};

    const int arow = (wr << 6) + (lane & 15);
    const int brow = (wc << 6) + (lane & 15);
    const int koff = (lane >> 4) << 3;

    for (int kt = 0; kt < K; kt += 32) {
        GLOAD16(ga0 + kt, la0);
        GLOAD16(ga0 + kt + (size_t)16 * lda, la0 + 512);
        GLOAD16(gb0 + kt, lb0);
        GLOAD16(gb0 + kt + (size_t)16 * ldb, lb0 + 512);
        __syncthreads();
        bf16x8 af[4], bfr[4];
        #pragma unroll
        for (int m = 0; m < 4; m++)
            af[m] = *(const bf16x8*)&As[(arow + (m << 4)) * 32 + koff];
        #pragma unroll
        for (int n = 0; n < 4; n++)
            bfr[n] = *(const bf16x8*)&Bs[(brow + (n << 4)) * 32 + koff];
        #pragma unroll
        for (int m = 0; m < 4; m++)
            #pragma unroll
            for (int n = 0; n < 4; n++)
                acc[m][n] = __builtin_amdgcn_mfma_f32_16x16x32_bf16(af[m], bfr[n], acc[m][n], 0, 0, 0);
        __syncthreads();
    }

    // epilogue: C/D layout col=lane&15, row=(lane>>4)*4+j
    const int r0 = (lane >> 4) << 2;
    const int c0 = lane & 15;

    if constexpr (EPI == GE_F32) {
        float* Cb = (float*)Cv + (size_t)z * sC;
        #pragma unroll
        for (int m = 0; m < 4; m++) {
            int gmb = m0 + (wr << 6) + (m << 4) + r0;
            #pragma unroll
            for (int j = 0; j < 4; j++) {
                float* crow = Cb + (size_t)(gmb + j) * ldc;
                #pragma unroll
                for (int n = 0; n < 4; n++)
                    crow[n0 + (wc << 6) + (n << 4) + c0] = acc[m][n][j];
            }
        }
    } else if constexpr (EPI == GE_BF16) {
        u16* Cb = (u16*)Cv + (size_t)z * sC;
        #pragma unroll
        for (int m = 0; m < 4; m++) {
            int gmb = m0 + (wr << 6) + (m << 4) + r0;
            #pragma unroll
            for (int j = 0; j < 4; j++) {
                u16* crow = Cb + (size_t)(gmb + j) * ldc;
                #pragma unroll
                for (int n = 0; n < 4; n++)
                    crow[n0 + (wc << 6) + (n << 4) + c0] = f2bf(acc[m][n][j]);
            }
        }
    } else if constexpr (EPI == GE_ADDH) {
        float* Cb = (float*)Cv + (size_t)z * sC;
        #pragma unroll
        for (int m = 0; m < 4; m++) {
            int gmb = m0 + (wr << 6) + (m << 4) + r0;
            #pragma unroll
            for (int j = 0; j < 4; j++) {
                float* crow = Cb + (size_t)(gmb + j) * ldc;
                #pragma unroll
                for (int n = 0; n < 4; n++) {
                    int gn = n0 + (wc << 6) + (n << 4) + c0;
                    crow[gn] = crow[gn] + acc[m][n][j] + bias[gn];
                }
            }
        }
    } else if constexpr (EPI == GE_RELU) {
        const bool aregion = (n0 < cE);
        #pragma unroll
        for (int m = 0; m < 4; m++) {
            const int gmb = m0 + (wr << 6) + (m << 4) + r0;
            const int zz = gmb >> 10, cm = gmb & 1023;
            #pragma unroll
            for (int n = 0; n < 4; n++) {
                const int gn = n0 + (wc << 6) + (n << 4) + c0;
                const float bv = bias[gn];
                u16 rb[4];
                #pragma unroll
                for (int j = 0; j < 4; j++) {
                    float tv = acc[m][n][j] + bv;
                    tv = fmaxf(tv, 0.f);
                    rb[j] = f2bf(tv * tv);
                }
                if (aregion) {
                    #pragma unroll
                    for (int j = 0; j < 4; j++)
                        p0[(size_t)(gmb + j) * cE + gn] = rb[j];
                    uint32_t lo = rb[0] | ((uint32_t)rb[1] << 16);
                    uint32_t hi = rb[2] | ((uint32_t)rb[3] << 16);
                    *(uint2*)&p1[(size_t)zz * (cE * cTL) + (size_t)gn * cTL + cm] = make_uint2(lo, hi);
                } else {
                    #pragma unroll
                    for (int j = 0; j < 4; j++)
                        p2[(size_t)(gmb + j) * cPIN + (gn - cE)] = rb[j];
                }
            }
        }
    } else if constexpr (EPI == GE_CS) {
        u16* Cb = (u16*)Cv + (size_t)z * sC;
        const float* invz = invn + (z << 10);
        float inn[4];
        #pragma unroll
        for (int n = 0; n < 4; n++)
            inn[n] = invz[n0 + (wc << 6) + (n << 4) + c0];
        #pragma unroll
        for (int m = 0; m < 4; m++) {
            int gmb = m0 + (wr << 6) + (m << 4) + r0;
            #pragma unroll
            for (int j = 0; j < 4; j++) {
                int gm = gmb + j;
                float im = invz[gm];
                const float* spr = sp + (size_t)gm * cTL;
                u16* crow = Cb + (size_t)gm * ldc;
                #pragma unroll
                for (int n = 0; n < 4; n++) {
                    int gn = n0 + (wc << 6) + (n << 4) + c0;
                    float v = (gn <= gm) ? acc[m][n][j] * im * inn[n] * spr[gn] : 0.f;
                    crow[gn] = f2bf(v);
                }
            }
        }
    }
}

// ---------------------------------------------------------------- launch
extern "C" void kernel_launch(void* const* d_in, const int* in_sizes, int n_in,
                              void* d_out, int out_size, void* d_ws, size_t ws_size,
                              hipStream_t stream) {
    const int*   ids  = (const int*)d_in[0];
    const float* wte  = (const float*)d_in[1];
    const float* rmsw = (const float*)d_in[2];
    const float* enrw = (const float*)d_in[3];
    const float* enrb = (const float*)d_in[4];
    const float* sp   = (const float*)d_in[5];
    const float* fusw = (const float*)d_in[6];
    const float* fusb = (const float*)d_in[7];
    const float* lnfw = (const float*)d_in[8];
    float* out = (float*)d_out;

    // fp32 workspace
    float* ws   = (float*)d_ws;
    float* x    = ws;                      // 3,145,728
    float* xnt  = x    + 3145728;          // 3,145,728
    float* h    = xnt  + 3145728;          // 12,582,912
    float* invn = h    + 12582912;         // 16,384
    float* part = invn + 16384;            // 256
    float* swv  = part + 256;              // 64
    int*   sidx = (int*)(swv + 64);        // 64
    // bf16 workspace
    u16* wteb  = (u16*)(sidx + 64);        // 24,576,000
    u16* enrwb = wteb  + 24576000;         //  9,437,184
    u16* fuswb = enrwb + 9437184;          //  7,077,888
    u16* xnb   = fuswb + 7077888;          // 12,582,912 (reused as finn bf16)
    u16* abuf  = xnb   + 12582912;         // 12,582,912
    u16* aTb   = abuf  + 12582912;         // 12,582,912
    u16* fi    = aTb   + 12582912;         // 37,748,736 (cols 0..767: b then a_new*b; 768..2303: x1)
    u16* csb   = fi    + 37748736;         // 16,777,216
    u16* anT   = csb   + 16777216;         // 12,582,912
    u16* finnb = xnb;

    // 0. weight conversion fp32->bf16
    cvt_k<<<24576000 / 1024, 256, 0, stream>>>(wte,  wteb,  24576000);
    cvt_k<<< 9437184 / 1024, 256, 0, stream>>>(enrw, enrwb,  9437184);
    cvt_k<<< 7077888 / 1024, 256, 0, stream>>>(fusw, fuswb,  7077888);

    // 1. embed + token normalize (fp32)
    embed_k<<<cB * cT, 256, 0, stream>>>(ids, wte, x, xnt);
    // 2. retrieval scores + top-k + assembly (fp32, deterministic)
    pair_scores_k<<<dim3(4, 56), 256, 0, stream>>>(xnt, part);
    score_topk_k<<<1, 64, 0, stream>>>(part, sidx, swv);
    build_k<<<dim3(cNCH, cTL), 192, 0, stream>>>(x, sidx, swv, h);

    // 3. layers
    for (int l = 0; l < cL; l++) {
        rmsnorm_bf_k<<<cMR, 256, 0, stream>>>(h, rmsw + (size_t)l * cE, xnb);
        // xp = relu(xn @ enr_w.T + b)^2 ; writes a (row-major + transposed) and b/x1 into fi
        gemm_bt<GE_RELU><<<dim3(cED / 128, cMR / 128, 1), 256, 0, stream>>>(
            xnb, cE, 0, enrwb + (size_t)l * cED * cE, cE, 0,
            nullptr, 0, 0, cE, enrb + (size_t)l * cED, nullptr, nullptr,
            abuf, aTb, fi);
        invna_bf_k<<<cMR, 256, 0, stream>>>(abuf, invn);
        // M = tril(sp) * cosine(a,a)
        gemm_bt<GE_CS><<<dim3(8, 8, cNCH), 256, 0, stream>>>(
            abuf, cE, (size_t)cTL * cE, abuf, cE, (size_t)cTL * cE,
            csb, cTL, (size_t)cTL * cTL, cE,
            nullptr, invn, sp + (size_t)l * cTL * cTL, nullptr, nullptr, nullptr);
        // a_newT[e][m] = sum_c aT[e][c] * M[m][c]
        gemm_bt<GE_BF16><<<dim3(8, 6, cNCH), 256, 0, stream>>>(
            aTb, cTL, (size_t)cE * cTL, csb, cTL, (size_t)cTL * cTL,
            anT, cTL, (size_t)cE * cTL, cTL,
            nullptr, nullptr, nullptr, nullptr, nullptr, nullptr);
        // fi[:, :768] = a_new * b (transpose + elementwise)
        tmul_k<<<dim3(16, 12, cNCH), 256, 0, stream>>>(anT, fi);
        // h += fi @ fus_w.T + fus_b
        gemm_bt<GE_ADDH><<<dim3(cE / 128, cMR / 128, 1), 256, 0, stream>>>(
            fi, cPIN, 0, fuswb + (size_t)l * cE * cPIN, cPIN, 0,
            h, cE, 0, cPIN, fusb + (size_t)l * cE, nullptr, nullptr,
            nullptr, nullptr, nullptr);
    }

    // 4. final norm + logits
    final_bf_k<<<cB * cT, 256, 0, stream>>>(h, lnfw, finnb);
    gemm_bt<GE_F32><<<dim3(cV / 128, (cB * cT) / 128, 1), 256, 0, stream>>>(
        finnb, cE, 0, wteb, cE, 0, out, cV, 0, cE,
        nullptr, nullptr, nullptr, nullptr, nullptr, nullptr);
}

// Round 3
// 2073.752 us; speedup vs baseline: 5.1549x; 1.0222x over previous
//
#include <hip/hip_runtime.h>
#include <math.h>

typedef unsigned short u16;
typedef __attribute__((ext_vector_type(8))) short bf16x8;
typedef __attribute__((ext_vector_type(4))) float f32x4;

// Problem constants
constexpr int cV = 32000, cE = 768, cL = 4, cC = 256, cTL = 1024;
constexpr int cED = 3072, cPIN = 2304;
constexpr int cB = 2, cT = 2048, cN = 8, cNCH = 16, cMR = 16384;

// ---------------------------------------------------------------- bf16 helpers
__device__ inline float bf2f(u16 u) {
    union { uint32_t i; float f; } v; v.i = ((uint32_t)u) << 16; return v.f;
}
__device__ inline u16 f2bf(float f) {
    union { float f; uint32_t u; } v; v.f = f;
    uint32_t r = v.u + 0x7FFF + ((v.u >> 16) & 1);
    return (u16)(r >> 16);
}

// async global->LDS, 16B per lane; LDS dest is wave-uniform base + lane*16
#define GLOAD16(gp, lp) __builtin_amdgcn_global_load_lds( \
    (const __attribute__((address_space(1))) void*)(gp), \
    (__attribute__((address_space(3))) void*)(lp), 16, 0, 0)

// ---------------------------------------------------------------- reductions
__device__ inline float blockReduceSum256(float v, float* sbuf) {
    #pragma unroll
    for (int m = 1; m < 64; m <<= 1) v += __shfl_xor(v, m, 64);
    int lane = threadIdx.x & 63, w = threadIdx.x >> 6;
    if (lane == 0) sbuf[w] = v;
    __syncthreads();
    return sbuf[0] + sbuf[1] + sbuf[2] + sbuf[3];
}

// ---------------------------------------------------------------- fp32 -> bf16 bulk convert
__global__ __launch_bounds__(256) void cvt_k(const float* __restrict__ in,
                                             u16* __restrict__ out, long n) {
    long i = ((long)blockIdx.x * 256 + threadIdx.x) * 4;
    if (i >= n) return;
    float4 v = *(const float4*)(in + i);
    uint32_t lo = f2bf(v.x) | ((uint32_t)f2bf(v.y) << 16);
    uint32_t hi = f2bf(v.z) | ((uint32_t)f2bf(v.w) << 16);
    *(uint2*)(out + i) = make_uint2(lo, hi);
}

// ---------------------------------------------------------------- embed + token-normalize (fp32, feeds topk)
__global__ __launch_bounds__(256) void embed_k(const int* __restrict__ ids,
                                               const float* __restrict__ wte,
                                               float* __restrict__ x,
                                               float* __restrict__ xnt) {
    __shared__ float sb[4];
    int tok = blockIdx.x;
    const float* src = wte + (size_t)ids[tok] * cE;
    int t = threadIdx.x;
    float v0 = src[t], v1 = src[t + 256], v2 = src[t + 512];
    float tot = blockReduceSum256(v0 * v0 + v1 * v1 + v2 * v2, sb);
    float inv = 1.0f / (sqrtf(tot) + 1e-8f);
    size_t o = (size_t)tok * cE + t;
    x[o] = v0; x[o + 256] = v1; x[o + 512] = v2;
    xnt[o] = v0 * inv; xnt[o + 256] = v1 * inv; xnt[o + 512] = v2 * inv;
}

// ---------------------------------------------------------------- rmsnorm -> bf16
__global__ __launch_bounds__(256) void rmsnorm_bf_k(const float* __restrict__ in,
                                                    const float* __restrict__ w,
                                                    u16* __restrict__ out) {
    __shared__ float sb[4];
    size_t row = blockIdx.x;
    const float* src = in + row * cE;
    int t = threadIdx.x;
    float v0 = src[t], v1 = src[t + 256], v2 = src[t + 512];
    float tot = blockReduceSum256(v0 * v0 + v1 * v1 + v2 * v2, sb);
    float s = 1.0f / sqrtf(tot * (1.0f / cE) + 1e-10f);
    out[row * cE + t]       = f2bf(v0 * s * w[t]);
    out[row * cE + t + 256] = f2bf(v1 * s * w[t + 256]);
    out[row * cE + t + 512] = f2bf(v2 * s * w[t + 512]);
}

// ---------------------------------------------------------------- inverse row norm of a (bf16 input)
__global__ __launch_bounds__(256) void invna_bf_k(const u16* __restrict__ a,
                                                  float* __restrict__ invna) {
    __shared__ float sb[4];
    size_t row = blockIdx.x;
    const u16* src = a + row * cE;
    int t = threadIdx.x;
    float v0 = bf2f(src[t]), v1 = bf2f(src[t + 256]), v2 = bf2f(src[t + 512]);
    float tot = blockReduceSum256(v0 * v0 + v1 * v1 + v2 * v2, sb);
    if (t == 0) invna[row] = 1.0f / sqrtf(tot + 1e-8f);
}

// ---------------------------------------------------------------- final row extract + rmsnorm(lnf) -> bf16
__global__ __launch_bounds__(256) void final_bf_k(const float* __restrict__ h,
                                                  const float* __restrict__ lnf,
                                                  u16* __restrict__ finn) {
    __shared__ float sb[4];
    int tok = blockIdx.x;
    int b = tok >> 11, tt = tok & 2047;
    int i = tt >> 8, c = tt & 255;
    size_t row = (size_t)(b * cN + i) * cTL + (cTL - cC) + c;
    const float* src = h + row * cE;
    int t = threadIdx.x;
    float v0 = src[t], v1 = src[t + 256], v2 = src[t + 512];
    float tot = blockReduceSum256(v0 * v0 + v1 * v1 + v2 * v2, sb);
    float s = 1.0f / sqrtf(tot * (1.0f / cE) + 1e-10f);
    size_t o = (size_t)tok * cE + t;
    finn[o]       = f2bf(v0 * s * lnf[t]);
    finn[o + 256] = f2bf(v1 * s * lnf[t + 256]);
    finn[o + 512] = f2bf(v2 * s * lnf[t + 512]);
}

// ---------------------------------------------------------------- pair scores v2: 4 waves, wave-per-nt, 8x8 microtile
// score contribution: sum_c max_k (xn_i[c] . xn_j[k]); max exact, sum order = rows 0..63 (bit-identical to v1)
__global__ __launch_bounds__(256) void pair_scores_k(const float* __restrict__ xnt,
                                                     float* __restrict__ partial) {
    __shared__ float As[16][64];
    __shared__ float Bs[4][16][64];
    __shared__ float rowmax[4][64];
    int ct = blockIdx.x;
    int p  = blockIdx.y;
    int b = p / 28, pp = p % 28;
    int i = 1; while (pp >= i) { pp -= i; i++; }
    int j = pp;
    const float* Abase = xnt + ((size_t)(b * cT) + i * cC + ct * 64) * cE;
    const float* Bbase = xnt + ((size_t)(b * cT) + j * cC) * cE;
    int tid = threadIdx.x, lane = tid & 63, w = tid >> 6;
    int ly = lane >> 3, lx = lane & 7;
    int srow = tid >> 2, skc = (tid & 3) << 2;
    const float* bw = Bbase + (size_t)(w * 64) * cE;

    float acc[8][8];
    #pragma unroll
    for (int a2 = 0; a2 < 8; a2++)
        #pragma unroll
        for (int b2 = 0; b2 < 8; b2++) acc[a2][b2] = 0.f;

    for (int k0 = 0; k0 < cE; k0 += 16) {
        // stage As (256 threads, one float4 each)
        float4 va = *(const float4*)(Abase + (size_t)srow * cE + k0 + skc);
        As[skc + 0][srow] = va.x; As[skc + 1][srow] = va.y;
        As[skc + 2][srow] = va.z; As[skc + 3][srow] = va.w;
        // stage Bs[w] (64 lanes, 4 float4 each)
        #pragma unroll
        for (int q = 0; q < 4; q++) {
            int id = (q << 6) + lane;
            int br = id >> 2, bkc = (id & 3) << 2;
            float4 vb = *(const float4*)(bw + (size_t)br * cE + k0 + bkc);
            Bs[w][bkc + 0][br] = vb.x; Bs[w][bkc + 1][br] = vb.y;
            Bs[w][bkc + 2][br] = vb.z; Bs[w][bkc + 3][br] = vb.w;
        }
        __syncthreads();
        #pragma unroll
        for (int k = 0; k < 16; k++) {
            float av[8], bv[8];
            *(float4*)&av[0] = *(float4*)&As[k][ly << 3];
            *(float4*)&av[4] = *(float4*)&As[k][(ly << 3) + 4];
            *(float4*)&bv[0] = *(float4*)&Bs[w][k][lx << 3];
            *(float4*)&bv[4] = *(float4*)&Bs[w][k][(lx << 3) + 4];
            #pragma unroll
            for (int r = 0; r < 8; r++)
                #pragma unroll
                for (int q = 0; q < 8; q++)
                    acc[r][q] = fmaf(av[r], bv[q], acc[r][q]);
        }
        __syncthreads();
    }
    // per-row max over this wave's 64 k-cols
    #pragma unroll
    for (int r = 0; r < 8; r++) {
        float m = acc[r][0];
        #pragma unroll
        for (int q = 1; q < 8; q++) m = fmaxf(m, acc[r][q]);
        m = fmaxf(m, __shfl_xor(m, 1, 64));
        m = fmaxf(m, __shfl_xor(m, 2, 64));
        m = fmaxf(m, __shfl_xor(m, 4, 64));
        if (lx == 0) rowmax[w][(ly << 3) + r] = m;
    }
    __syncthreads();
    if (tid == 0) {
        float s = 0.f;
        for (int r = 0; r < 64; r++)
            s += fmaxf(fmaxf(rowmax[0][r], rowmax[1][r]),
                       fmaxf(rowmax[2][r], rowmax[3][r]));
        partial[p * 4 + ct] = s;   // fixed order -> deterministic
    }
}

// ---------------------------------------------------------------- top-k + sort + weights (unchanged)
__global__ void score_topk_k(const float* __restrict__ partial,
                             int* __restrict__ sidx, float* __restrict__ sw) {
    __shared__ float sc[2][8][8];
    int t = threadIdx.x;
    if (t < 56) {
        int b = t / 28, pp = t % 28;
        int i = 1; while (pp >= i) { pp -= i; i++; }
        int j = pp;
        sc[b][i][j] = partial[t * 4 + 0] + partial[t * 4 + 1] + partial[t * 4 + 2] + partial[t * 4 + 3];
    }
    __syncthreads();
    if (t < 16) {
        int b = t >> 3, i = t & 7;
        int nsel = i < 3 ? i : 3;
        if (nsel > 0) {
            float loc[7];
            for (int j2 = 0; j2 < i; j2++) loc[j2] = sc[b][i][j2];
            int idxs[3]; float vals[3];
            for (int s = 0; s < nsel; s++) {
                int am = 0; float mv = loc[0];
                for (int j2 = 1; j2 < i; j2++) if (loc[j2] > mv) { mv = loc[j2]; am = j2; }
                idxs[s] = am; vals[s] = mv; loc[am] = -1e30f;
            }
            for (int a = 0; a < nsel; a++)
                for (int c2 = a + 1; c2 < nsel; c2++)
                    if (idxs[c2] < idxs[a]) {
                        int ti = idxs[a]; idxs[a] = idxs[c2]; idxs[c2] = ti;
                        float tv = vals[a]; vals[a] = vals[c2]; vals[c2] = tv;
                    }
            float den = vals[0] + 1e-8f;
            for (int s = 0; s < nsel; s++) {
                sidx[(b * 8 + i) * 3 + s] = idxs[s];
                sw[(b * 8 + i) * 3 + s]   = vals[s] / den;
            }
        }
    }
}

// ---------------------------------------------------------------- assemble extended context h (fp32)
__global__ __launch_bounds__(192) void build_k(const float* __restrict__ x,
                                               const int* __restrict__ sidx,
                                               const float* __restrict__ sw,
                                               float* __restrict__ h) {
    int m = blockIdx.x, r = blockIdx.y;
    int b = m >> 3, i = m & 7;
    int nsel = i < 3 ? i : 3;
    int pad = cTL - (nsel + 1) * cC;
    int pos = r - pad;
    float4 val = make_float4(0.f, 0.f, 0.f, 0.f);
    if (pos >= 0) {
        if (pos < nsel * cC) {
            int s = pos >> 8;
            int jj = sidx[(b * 8 + i) * 3 + s];
            float wg = sw[(b * 8 + i) * 3 + s];
            const float4* src = (const float4*)(x + ((size_t)(b * cT) + jj * cC + (pos & 255)) * cE);
            float4 v = src[threadIdx.x];
            val = make_float4(v.x * wg, v.y * wg, v.z * wg, v.w * wg);
        } else {
            int c = pos - nsel * cC;
            const float4* src = (const float4*)(x + ((size_t)(b * cT) + i * cC + c) * cE);
            val = src[threadIdx.x];
        }
    }
    ((float4*)(h + ((size_t)m * cTL + r) * cE))[threadIdx.x] = val;
}

// ---------------------------------------------------------------- transpose(a_newT) * fi[:, :768] -> fi[:, :768]
__global__ __launch_bounds__(256) void tmul_k(const u16* __restrict__ anT,
                                              u16* __restrict__ fi) {
    __shared__ u16 tile[64][65];
    int c0 = blockIdx.x << 6, j0 = blockIdx.y << 6, z = blockIdx.z;
    const u16* src = anT + (size_t)z * (cE * cTL);
    int t = threadIdx.x;
    #pragma unroll
    for (int it = 0; it < 16; it++) {
        int id = t + (it << 8);
        int r = id >> 6, c = id & 63;
        tile[r][c] = src[(size_t)(j0 + r) * cTL + c0 + c];
    }
    __syncthreads();
    #pragma unroll
    for (int it = 0; it < 16; it++) {
        int id = t + (it << 8);
        int cm = id >> 6, jj = id & 63;
        size_t o = (size_t)(z * cTL + c0 + cm) * cPIN + j0 + jj;
        fi[o] = f2bf(bf2f(tile[jj][cm]) * bf2f(fi[o]));
    }
}

// ---------------------------------------------------------------- bf16 MFMA GEMM (m97 structure)
// NT: C[m,n] = sum_k A[m*lda+k] * B[n*ldb+k]; 128x128 tile, BK=32, 4 waves, 16x16x32 MFMA
// swz: 0 none; 1 XCD-chunked, x-fastest decode; 2 XCD-chunked, y-fastest decode (nwg%8==0 required)
// kcap: if 1, K_eff = min(K, n0+128)  (tril-aware K truncation for the a_newT GEMM)
enum { GE_F32 = 0, GE_RELU = 1, GE_CS = 2, GE_ADDH = 3, GE_BF16 = 4 };

template <int EPI>
__global__ __launch_bounds__(256) void gemm_bt(
        const u16* __restrict__ A, int lda, size_t sA,
        const u16* __restrict__ B, int ldb, size_t sB,
        void* __restrict__ Cv, int ldc, size_t sC, int K,
        const float* __restrict__ bias,
        const float* __restrict__ invn,
        const float* __restrict__ sp,
        u16* __restrict__ p0, u16* __restrict__ p1, u16* __restrict__ p2,
        int swz, int kcap)
{
    int bx = blockIdx.x, by = blockIdx.y;
    if (swz) {
        int gx = gridDim.x, gy = gridDim.y;
        int nwg = gx * gy;
        int orig = by * gx + bx;
        int wg = (orig & 7) * (nwg >> 3) + (orig >> 3);   // XCD-contiguous chunks
        if (swz == 1) { bx = wg % gx; by = wg / gx; }
        else          { by = wg % gy; bx = wg / gy; }
    }
    const int n0 = bx << 7, m0 = by << 7, z = blockIdx.z;
    const int tid = threadIdx.x, lane = tid & 63, w = tid >> 6;
    const int wr = w >> 1, wc = w & 1;

    if constexpr (EPI == GE_CS) {
        if (n0 > m0) return;   // strictly-upper blocks never read downstream (K-capped consumer)
    }

    const int Keff = kcap ? ((K < n0 + 128) ? K : n0 + 128) : K;

    __shared__ __align__(16) u16 As[128 * 32];
    __shared__ __align__(16) u16 Bs[128 * 32];

    const u16* Ab = A + (size_t)z * sA + (size_t)m0 * lda;
    const u16* Bb = B + (size_t)z * sB + (size_t)n0 * ldb;

    // staging: wave w covers rows [w*32, w*32+32) in two 1KB chunks (16 rows each)
    const int srow = (w << 5) + (lane >> 2);
    const int skof = (lane & 3) << 3;
    const u16* ga0 = Ab + (size_t)srow * lda + skof;
    const u16* gb0 = Bb + (size_t)srow * ldb + skof;
    u16* la0 = As + (w << 10);
    u16* lb0 = Bs + (w << 10);

    f32x4 acc[4][4];
    #pragma unroll
    for (int m = 0; m < 4; m++)
        #pragma unroll
        for (int n = 0; n < 4; n++)
            acc[m][n] = (f32x4){0.f, 0.f, 0.f, 0.f};

    const int arow = (wr << 6) + (lane & 15);
    const int brow = (wc << 6) + (lane & 15);
    const int koff = (lane >> 4) << 3;

    for (int kt = 0; kt < Keff; kt += 32) {
        GLOAD16(ga0 + kt, la0);
        GLOAD16(ga0 + kt + (size_t)16 * lda, la0 + 512);
        GLOAD16(gb0 + kt, lb0);
        GLOAD16(gb0 + kt + (size_t)16 * ldb, lb0 + 512);
        __syncthreads();
        bf16x8 af[4], bfr[4];
        #pragma unroll
        for (int m = 0; m < 4; m++)
            af[m] = *(const bf16x8*)&As[(arow + (m << 4)) * 32 + koff];
        #pragma unroll
        for (int n = 0; n < 4; n++)
            bfr[n] = *(const bf16x8*)&Bs[(brow + (n << 4)) * 32 + koff];
        #pragma unroll
        for (int m = 0; m < 4; m++)
            #pragma unroll
            for (int n = 0; n < 4; n++)
                acc[m][n] = __builtin_amdgcn_mfma_f32_16x16x32_bf16(af[m], bfr[n], acc[m][n], 0, 0, 0);
        __syncthreads();
    }

    // epilogue: C/D layout col=lane&15, row=(lane>>4)*4+j
    const int r0 = (lane >> 4) << 2;
    const int c0 = lane & 15;

    if constexpr (EPI == GE_F32) {
        float* Cb = (float*)Cv + (size_t)z * sC;
        #pragma unroll
        for (int m = 0; m < 4; m++) {
            int gmb = m0 + (wr << 6) + (m << 4) + r0;
            #pragma unroll
            for (int j = 0; j < 4; j++) {
                float* crow = Cb + (size_t)(gmb + j) * ldc;
                #pragma unroll
                for (int n = 0; n < 4; n++)
                    crow[n0 + (wc << 6) + (n << 4) + c0] = acc[m][n][j];
            }
        }
    } else if constexpr (EPI == GE_BF16) {
        u16* Cb = (u16*)Cv + (size_t)z * sC;
        #pragma unroll
        for (int m = 0; m < 4; m++) {
            int gmb = m0 + (wr << 6) + (m << 4) + r0;
            #pragma unroll
            for (int j = 0; j < 4; j++) {
                u16* crow = Cb + (size_t)(gmb + j) * ldc;
                #pragma unroll
                for (int n = 0; n < 4; n++)
                    crow[n0 + (wc << 6) + (n << 4) + c0] = f2bf(acc[m][n][j]);
            }
        }
    } else if constexpr (EPI == GE_ADDH) {
        float* Cb = (float*)Cv + (size_t)z * sC;
        #pragma unroll
        for (int m = 0; m < 4; m++) {
            int gmb = m0 + (wr << 6) + (m << 4) + r0;
            #pragma unroll
            for (int j = 0; j < 4; j++) {
                float* crow = Cb + (size_t)(gmb + j) * ldc;
                #pragma unroll
                for (int n = 0; n < 4; n++) {
                    int gn = n0 + (wc << 6) + (n << 4) + c0;
                    crow[gn] = crow[gn] + acc[m][n][j] + bias[gn];
                }
            }
        }
    } else if constexpr (EPI == GE_RELU) {
        const bool aregion = (n0 < cE);
        #pragma unroll
        for (int m = 0; m < 4; m++) {
            const int gmb = m0 + (wr << 6) + (m << 4) + r0;
            const int zz = gmb >> 10, cm = gmb & 1023;
            #pragma unroll
            for (int n = 0; n < 4; n++) {
                const int gn = n0 + (wc << 6) + (n << 4) + c0;
                const float bv = bias[gn];
                u16 rb[4];
                #pragma unroll
                for (int j = 0; j < 4; j++) {
                    float tv = acc[m][n][j] + bv;
                    tv = fmaxf(tv, 0.f);
                    rb[j] = f2bf(tv * tv);
                }
                if (aregion) {
                    #pragma unroll
                    for (int j = 0; j < 4; j++)
                        p0[(size_t)(gmb + j) * cE + gn] = rb[j];
                    uint32_t lo = rb[0] | ((uint32_t)rb[1] << 16);
                    uint32_t hi = rb[2] | ((uint32_t)rb[3] << 16);
                    *(uint2*)&p1[(size_t)zz * (cE * cTL) + (size_t)gn * cTL + cm] = make_uint2(lo, hi);
                } else {
                    #pragma unroll
                    for (int j = 0; j < 4; j++)
                        p2[(size_t)(gmb + j) * cPIN + (gn - cE)] = rb[j];
                }
            }
        }
    } else if constexpr (EPI == GE_CS) {
        u16* Cb = (u16*)Cv + (size_t)z * sC;
        const float* invz = invn + (z << 10);
        float inn[4];
        #pragma unroll
        for (int n = 0; n < 4; n++)
            inn[n] = invz[n0 + (wc << 6) + (n << 4) + c0];
        #pragma unroll
        for (int m = 0; m < 4; m++) {
            int gmb = m0 + (wr << 6) + (m << 4) + r0;
            #pragma unroll
            for (int j = 0; j < 4; j++) {
                int gm = gmb + j;
                float im = invz[gm];
                const float* spr = sp + (size_t)gm * cTL;
                u16* crow = Cb + (size_t)gm * ldc;
                #pragma unroll
                for (int n = 0; n < 4; n++) {
                    int gn = n0 + (wc << 6) + (n << 4) + c0;
                    float v = (gn <= gm) ? acc[m][n][j] * im * inn[n] * spr[gn] : 0.f;
                    crow[gn] = f2bf(v);
                }
            }
        }
    }
}

// ---------------------------------------------------------------- launch
extern "C" void kernel_launch(void* const* d_in, const int* in_sizes, int n_in,
                              void* d_out, int out_size, void* d_ws, size_t ws_size,
                              hipStream_t stream) {
    const int*   ids  = (const int*)d_in[0];
    const float* wte  = (const float*)d_in[1];
    const float* rmsw = (const float*)d_in[2];
    const float* enrw = (const float*)d_in[3];
    const float* enrb = (const float*)d_in[4];
    const float* sp   = (const float*)d_in[5];
    const float* fusw = (const float*)d_in[6];
    const float* fusb = (const float*)d_in[7];
    const float* lnfw = (const float*)d_in[8];
    float* out = (float*)d_out;

    // fp32 workspace
    float* ws   = (float*)d_ws;
    float* x    = ws;                      // 3,145,728
    float* xnt  = x    + 3145728;          // 3,145,728
    float* h    = xnt  + 3145728;          // 12,582,912
    float* invn = h    + 12582912;         // 16,384
    float* part = invn + 16384;            // 256
    float* swv  = part + 256;              // 64
    int*   sidx = (int*)(swv + 64);        // 64
    // bf16 workspace
    u16* wteb  = (u16*)(sidx + 64);        // 24,576,000
    u16* enrwb = wteb  + 24576000;         //  9,437,184
    u16* fuswb = enrwb + 9437184;          //  7,077,888
    u16* xnb   = fuswb + 7077888;          // 12,582,912 (reused as finn bf16)
    u16* abuf  = xnb   + 12582912;         // 12,582,912
    u16* aTb   = abuf  + 12582912;         // 12,582,912
    u16* fi    = aTb   + 12582912;         // 37,748,736 (cols 0..767: b then a_new*b; 768..2303: x1)
    u16* csb   = fi    + 37748736;         // 16,777,216
    u16* anT   = csb   + 16777216;         // 12,582,912
    u16* finnb = xnb;

    // 0. weight conversion fp32->bf16
    cvt_k<<<24576000 / 1024, 256, 0, stream>>>(wte,  wteb,  24576000);
    cvt_k<<< 9437184 / 1024, 256, 0, stream>>>(enrw, enrwb,  9437184);
    cvt_k<<< 7077888 / 1024, 256, 0, stream>>>(fusw, fuswb,  7077888);

    // 1. embed + token normalize (fp32)
    embed_k<<<cB * cT, 256, 0, stream>>>(ids, wte, x, xnt);
    // 2. retrieval scores + top-k + assembly (fp32, deterministic)
    pair_scores_k<<<dim3(4, 56), 256, 0, stream>>>(xnt, part);
    score_topk_k<<<1, 64, 0, stream>>>(part, sidx, swv);
    build_k<<<dim3(cNCH, cTL), 192, 0, stream>>>(x, sidx, swv, h);

    // 3. layers
    for (int l = 0; l < cL; l++) {
        rmsnorm_bf_k<<<cMR, 256, 0, stream>>>(h, rmsw + (size_t)l * cE, xnb);
        // xp = relu(xn @ enr_w.T + b)^2 ; writes a (row-major + transposed) and b/x1 into fi
        gemm_bt<GE_RELU><<<dim3(cED / 128, cMR / 128, 1), 256, 0, stream>>>(
            xnb, cE, 0, enrwb + (size_t)l * cED * cE, cE, 0,
            nullptr, 0, 0, cE, enrb + (size_t)l * cED, nullptr, nullptr,
            abuf, aTb, fi, 1, 0);
        invna_bf_k<<<cMR, 256, 0, stream>>>(abuf, invn);
        // M = tril(sp) * cosine(a,a)   (strictly-upper blocks skipped, never read)
        gemm_bt<GE_CS><<<dim3(8, 8, cNCH), 256, 0, stream>>>(
            abuf, cE, (size_t)cTL * cE, abuf, cE, (size_t)cTL * cE,
            csb, cTL, (size_t)cTL * cTL, cE,
            nullptr, invn, sp + (size_t)l * cTL * cTL, nullptr, nullptr, nullptr, 0, 0);
        // a_newT[e][m] = sum_c aT[e][c] * M[m][c]  (K capped at n0+128 by tril)
        gemm_bt<GE_BF16><<<dim3(8, 6, cNCH), 256, 0, stream>>>(
            aTb, cTL, (size_t)cE * cTL, csb, cTL, (size_t)cTL * cTL,
            anT, cTL, (size_t)cE * cTL, cTL,
            nullptr, nullptr, nullptr, nullptr, nullptr, nullptr, 0, 1);
        // fi[:, :768] = a_new * b (transpose + elementwise)
        tmul_k<<<dim3(16, 12, cNCH), 256, 0, stream>>>(anT, fi);
        // h += fi @ fus_w.T + fus_b
        gemm_bt<GE_ADDH><<<dim3(cE / 128, cMR / 128, 1), 256, 0, stream>>>(
            fi, cPIN, 0, fuswb + (size_t)l * cE * cPIN, cPIN, 0,
            h, cE, 0, cPIN, fusb + (size_t)l * cE, nullptr, nullptr,
            nullptr, nullptr, nullptr, 1, 0);
    }

    // 4. final norm + logits
    final_bf_k<<<cB * cT, 256, 0, stream>>>(h, lnfw, finnb);
    gemm_bt<GE_F32><<<dim3(cV / 128, (cB * cT) / 128, 1), 256, 0, stream>>>(
        finnb, cE, 0, wteb, cE, 0, out, cV, 0, cE,
        nullptr, nullptr, nullptr, nullptr, nullptr, nullptr, 2, 0);
}

// Round 4
// 1916.698 us; speedup vs baseline: 5.5773x; 1.0819x over previous
//
#include <hip/hip_runtime.h>
#include <math.h>

typedef unsigned short u16;
typedef __attribute__((ext_vector_type(8))) short bf16x8;
typedef __attribute__((ext_vector_type(4))) float f32x4;

// Problem constants
constexpr int cV = 32000, cE = 768, cL = 4, cC = 256, cTL = 1024;
constexpr int cED = 3072, cPIN = 2304;
constexpr int cB = 2, cT = 2048, cN = 8, cNCH = 16, cMR = 16384;

// ---------------------------------------------------------------- bf16 helpers
__device__ inline float bf2f(u16 u) {
    union { uint32_t i; float f; } v; v.i = ((uint32_t)u) << 16; return v.f;
}
__device__ inline u16 f2bf(float f) {
    union { float f; uint32_t u; } v; v.f = f;
    uint32_t r = v.u + 0x7FFF + ((v.u >> 16) & 1);
    return (u16)(r >> 16);
}

// async global->LDS, 16B per lane; LDS dest is wave-uniform base + lane*16
#define GLOAD16(gp, lp) __builtin_amdgcn_global_load_lds( \
    (const __attribute__((address_space(1))) void*)(gp), \
    (__attribute__((address_space(3))) void*)(lp), 16, 0, 0)

// ---------------------------------------------------------------- reductions
__device__ inline float blockReduceSum256(float v, float* sbuf) {
    #pragma unroll
    for (int m = 1; m < 64; m <<= 1) v += __shfl_xor(v, m, 64);
    int lane = threadIdx.x & 63, w = threadIdx.x >> 6;
    if (lane == 0) sbuf[w] = v;
    __syncthreads();
    return sbuf[0] + sbuf[1] + sbuf[2] + sbuf[3];
}

// ---------------------------------------------------------------- fp32 -> bf16 bulk convert
__global__ __launch_bounds__(256) void cvt_k(const float* __restrict__ in,
                                             u16* __restrict__ out, long n) {
    long i = ((long)blockIdx.x * 256 + threadIdx.x) * 4;
    if (i >= n) return;
    float4 v = *(const float4*)(in + i);
    uint32_t lo = f2bf(v.x) | ((uint32_t)f2bf(v.y) << 16);
    uint32_t hi = f2bf(v.z) | ((uint32_t)f2bf(v.w) << 16);
    *(uint2*)(out + i) = make_uint2(lo, hi);
}

// ---------------------------------------------------------------- embed + token-normalize (fp32, feeds topk)
__global__ __launch_bounds__(256) void embed_k(const int* __restrict__ ids,
                                               const float* __restrict__ wte,
                                               float* __restrict__ x,
                                               float* __restrict__ xnt) {
    __shared__ float sb[4];
    int tok = blockIdx.x;
    const float* src = wte + (size_t)ids[tok] * cE;
    int t = threadIdx.x;
    float v0 = src[t], v1 = src[t + 256], v2 = src[t + 512];
    float tot = blockReduceSum256(v0 * v0 + v1 * v1 + v2 * v2, sb);
    float inv = 1.0f / (sqrtf(tot) + 1e-8f);
    size_t o = (size_t)tok * cE + t;
    x[o] = v0; x[o + 256] = v1; x[o + 512] = v2;
    xnt[o] = v0 * inv; xnt[o + 256] = v1 * inv; xnt[o + 512] = v2 * inv;
}

// ---------------------------------------------------------------- rmsnorm -> bf16
__global__ __launch_bounds__(256) void rmsnorm_bf_k(const float* __restrict__ in,
                                                    const float* __restrict__ w,
                                                    u16* __restrict__ out) {
    __shared__ float sb[4];
    size_t row = blockIdx.x;
    const float* src = in + row * cE;
    int t = threadIdx.x;
    float v0 = src[t], v1 = src[t + 256], v2 = src[t + 512];
    float tot = blockReduceSum256(v0 * v0 + v1 * v1 + v2 * v2, sb);
    float s = 1.0f / sqrtf(tot * (1.0f / cE) + 1e-10f);
    out[row * cE + t]       = f2bf(v0 * s * w[t]);
    out[row * cE + t + 256] = f2bf(v1 * s * w[t + 256]);
    out[row * cE + t + 512] = f2bf(v2 * s * w[t + 512]);
}

// ---------------------------------------------------------------- inverse row norm of a (bf16 input)
__global__ __launch_bounds__(256) void invna_bf_k(const u16* __restrict__ a,
                                                  float* __restrict__ invna) {
    __shared__ float sb[4];
    size_t row = blockIdx.x;
    const u16* src = a + row * cE;
    int t = threadIdx.x;
    float v0 = bf2f(src[t]), v1 = bf2f(src[t + 256]), v2 = bf2f(src[t + 512]);
    float tot = blockReduceSum256(v0 * v0 + v1 * v1 + v2 * v2, sb);
    if (t == 0) invna[row] = 1.0f / sqrtf(tot + 1e-8f);
}

// ---------------------------------------------------------------- final row extract + rmsnorm(lnf) -> bf16
__global__ __launch_bounds__(256) void final_bf_k(const float* __restrict__ h,
                                                  const float* __restrict__ lnf,
                                                  u16* __restrict__ finn) {
    __shared__ float sb[4];
    int tok = blockIdx.x;
    int b = tok >> 11, tt = tok & 2047;
    int i = tt >> 8, c = tt & 255;
    size_t row = (size_t)(b * cN + i) * cTL + (cTL - cC) + c;
    const float* src = h + row * cE;
    int t = threadIdx.x;
    float v0 = src[t], v1 = src[t + 256], v2 = src[t + 512];
    float tot = blockReduceSum256(v0 * v0 + v1 * v1 + v2 * v2, sb);
    float s = 1.0f / sqrtf(tot * (1.0f / cE) + 1e-10f);
    size_t o = (size_t)tok * cE + t;
    finn[o]       = f2bf(v0 * s * lnf[t]);
    finn[o + 256] = f2bf(v1 * s * lnf[t + 256]);
    finn[o + 512] = f2bf(v2 * s * lnf[t + 512]);
}

// ---------------------------------------------------------------- pair scores v2 (fp32, deterministic)
__global__ __launch_bounds__(256) void pair_scores_k(const float* __restrict__ xnt,
                                                     float* __restrict__ partial) {
    __shared__ float As[16][64];
    __shared__ float Bs[4][16][64];
    __shared__ float rowmax[4][64];
    int ct = blockIdx.x;
    int p  = blockIdx.y;
    int b = p / 28, pp = p % 28;
    int i = 1; while (pp >= i) { pp -= i; i++; }
    int j = pp;
    const float* Abase = xnt + ((size_t)(b * cT) + i * cC + ct * 64) * cE;
    const float* Bbase = xnt + ((size_t)(b * cT) + j * cC) * cE;
    int tid = threadIdx.x, lane = tid & 63, w = tid >> 6;
    int ly = lane >> 3, lx = lane & 7;
    int srow = tid >> 2, skc = (tid & 3) << 2;
    const float* bw = Bbase + (size_t)(w * 64) * cE;

    float acc[8][8];
    #pragma unroll
    for (int a2 = 0; a2 < 8; a2++)
        #pragma unroll
        for (int b2 = 0; b2 < 8; b2++) acc[a2][b2] = 0.f;

    for (int k0 = 0; k0 < cE; k0 += 16) {
        float4 va = *(const float4*)(Abase + (size_t)srow * cE + k0 + skc);
        As[skc + 0][srow] = va.x; As[skc + 1][srow] = va.y;
        As[skc + 2][srow] = va.z; As[skc + 3][srow] = va.w;
        #pragma unroll
        for (int q = 0; q < 4; q++) {
            int id = (q << 6) + lane;
            int br = id >> 2, bkc = (id & 3) << 2;
            float4 vb = *(const float4*)(bw + (size_t)br * cE + k0 + bkc);
            Bs[w][bkc + 0][br] = vb.x; Bs[w][bkc + 1][br] = vb.y;
            Bs[w][bkc + 2][br] = vb.z; Bs[w][bkc + 3][br] = vb.w;
        }
        __syncthreads();
        #pragma unroll
        for (int k = 0; k < 16; k++) {
            float av[8], bv[8];
            *(float4*)&av[0] = *(float4*)&As[k][ly << 3];
            *(float4*)&av[4] = *(float4*)&As[k][(ly << 3) + 4];
            *(float4*)&bv[0] = *(float4*)&Bs[w][k][lx << 3];
            *(float4*)&bv[4] = *(float4*)&Bs[w][k][(lx << 3) + 4];
            #pragma unroll
            for (int r = 0; r < 8; r++)
                #pragma unroll
                for (int q = 0; q < 8; q++)
                    acc[r][q] = fmaf(av[r], bv[q], acc[r][q]);
        }
        __syncthreads();
    }
    #pragma unroll
    for (int r = 0; r < 8; r++) {
        float m = acc[r][0];
        #pragma unroll
        for (int q = 1; q < 8; q++) m = fmaxf(m, acc[r][q]);
        m = fmaxf(m, __shfl_xor(m, 1, 64));
        m = fmaxf(m, __shfl_xor(m, 2, 64));
        m = fmaxf(m, __shfl_xor(m, 4, 64));
        if (lx == 0) rowmax[w][(ly << 3) + r] = m;
    }
    __syncthreads();
    if (tid == 0) {
        float s = 0.f;
        for (int r = 0; r < 64; r++)
            s += fmaxf(fmaxf(rowmax[0][r], rowmax[1][r]),
                       fmaxf(rowmax[2][r], rowmax[3][r]));
        partial[p * 4 + ct] = s;
    }
}

// ---------------------------------------------------------------- top-k + sort + weights (unchanged)
__global__ void score_topk_k(const float* __restrict__ partial,
                             int* __restrict__ sidx, float* __restrict__ sw) {
    __shared__ float sc[2][8][8];
    int t = threadIdx.x;
    if (t < 56) {
        int b = t / 28, pp = t % 28;
        int i = 1; while (pp >= i) { pp -= i; i++; }
        int j = pp;
        sc[b][i][j] = partial[t * 4 + 0] + partial[t * 4 + 1] + partial[t * 4 + 2] + partial[t * 4 + 3];
    }
    __syncthreads();
    if (t < 16) {
        int b = t >> 3, i = t & 7;
        int nsel = i < 3 ? i : 3;
        if (nsel > 0) {
            float loc[7];
            for (int j2 = 0; j2 < i; j2++) loc[j2] = sc[b][i][j2];
            int idxs[3]; float vals[3];
            for (int s = 0; s < nsel; s++) {
                int am = 0; float mv = loc[0];
                for (int j2 = 1; j2 < i; j2++) if (loc[j2] > mv) { mv = loc[j2]; am = j2; }
                idxs[s] = am; vals[s] = mv; loc[am] = -1e30f;
            }
            for (int a = 0; a < nsel; a++)
                for (int c2 = a + 1; c2 < nsel; c2++)
                    if (idxs[c2] < idxs[a]) {
                        int ti = idxs[a]; idxs[a] = idxs[c2]; idxs[c2] = ti;
                        float tv = vals[a]; vals[a] = vals[c2]; vals[c2] = tv;
                    }
            float den = vals[0] + 1e-8f;
            for (int s = 0; s < nsel; s++) {
                sidx[(b * 8 + i) * 3 + s] = idxs[s];
                sw[(b * 8 + i) * 3 + s]   = vals[s] / den;
            }
        }
    }
}

// ---------------------------------------------------------------- assemble extended context h (fp32)
__global__ __launch_bounds__(192) void build_k(const float* __restrict__ x,
                                               const int* __restrict__ sidx,
                                               const float* __restrict__ sw,
                                               float* __restrict__ h) {
    int m = blockIdx.x, r = blockIdx.y;
    int b = m >> 3, i = m & 7;
    int nsel = i < 3 ? i : 3;
    int pad = cTL - (nsel + 1) * cC;
    int pos = r - pad;
    float4 val = make_float4(0.f, 0.f, 0.f, 0.f);
    if (pos >= 0) {
        if (pos < nsel * cC) {
            int s = pos >> 8;
            int jj = sidx[(b * 8 + i) * 3 + s];
            float wg = sw[(b * 8 + i) * 3 + s];
            const float4* src = (const float4*)(x + ((size_t)(b * cT) + jj * cC + (pos & 255)) * cE);
            float4 v = src[threadIdx.x];
            val = make_float4(v.x * wg, v.y * wg, v.z * wg, v.w * wg);
        } else {
            int c = pos - nsel * cC;
            const float4* src = (const float4*)(x + ((size_t)(b * cT) + i * cC + c) * cE);
            val = src[threadIdx.x];
        }
    }
    ((float4*)(h + ((size_t)m * cTL + r) * cE))[threadIdx.x] = val;
}

// ---------------------------------------------------------------- transpose(a_newT) * fi[:, :768] -> fi[:, :768]
__global__ __launch_bounds__(256) void tmul_k(const u16* __restrict__ anT,
                                              u16* __restrict__ fi) {
    __shared__ u16 tile[64][65];
    int c0 = blockIdx.x << 6, j0 = blockIdx.y << 6, z = blockIdx.z;
    const u16* src = anT + (size_t)z * (cE * cTL);
    int t = threadIdx.x;
    #pragma unroll
    for (int it = 0; it < 16; it++) {
        int id = t + (it << 8);
        int r = id >> 6, c = id & 63;
        tile[r][c] = src[(size_t)(j0 + r) * cTL + c0 + c];
    }
    __syncthreads();
    #pragma unroll
    for (int it = 0; it < 16; it++) {
        int id = t + (it << 8);
        int cm = id >> 6, jj = id & 63;
        size_t o = (size_t)(z * cTL + c0 + cm) * cPIN + j0 + jj;
        fi[o] = f2bf(bf2f(tile[jj][cm]) * bf2f(fi[o]));
    }
}

enum { GE_F32 = 0, GE_RELU = 1, GE_CS = 2, GE_ADDH = 3, GE_BF16 = 4 };

// ---------------------------------------------------------------- 256x256 MFMA GEMM (T2+T4+T5)
// NT: C[m,n] = sum_k A[m*lda+k] * B[n*ldb+k]; BK=64, 8 waves (2Mx4N), 128KB LDS dbuf,
// counted vmcnt (never 0 in steady state), (row&7)<<4 XOR swizzle (both-sides), setprio MFMA.
template <int EPI>
__global__ __launch_bounds__(512, 2) void gemm256(
        const u16* __restrict__ A, int lda,
        const u16* __restrict__ B, int ldb,
        void* __restrict__ Cv, int ldc, int K,
        const float* __restrict__ bias,
        u16* __restrict__ p0, u16* __restrict__ p1, u16* __restrict__ p2,
        int swz)
{
    __shared__ __align__(16) u16 lds[65536];   // [buf:2][op:2][16384 u16] = 128 KiB
    int bx = blockIdx.x, by = blockIdx.y;
    if (swz == 3) {   // XCD owns gy/8 m-tiles; all XCDs sweep n in sync (B via L3, A chunk in L2)
        int gx = gridDim.x, gy = gridDim.y;
        int orig = by * gx + bx;
        int mpx = gy >> 3;
        int xcd = orig & 7, idx = orig >> 3;
        by = xcd * mpx + idx % mpx;
        bx = idx / mpx;
        (void)gx;
    }
    const int n0 = bx << 8, m0 = by << 8;
    const int tid = threadIdx.x, lane = tid & 63, w = tid >> 6;
    const int wm = w >> 2, wn = w & 3;

    const u16* Ab = A + (size_t)m0 * lda;
    const u16* Bb = B + (size_t)n0 * ldb;
    // staging source: LDS offset p=tid*16 within 8KB unit; logical q = p ^ ((row&7)<<4)
    const int rowoff = tid >> 3;                                   // 0..63
    const int kswz   = ((tid & 7) ^ (rowoff & 7)) << 3;            // u16 offset within 64-col row
    u16* sdst = lds + (w << 9);                                    // wave-uniform LDS base

    f32x4 acc[8][4];
    #pragma unroll
    for (int m = 0; m < 8; m++)
        #pragma unroll
        for (int n = 0; n < 4; n++) acc[m][n] = (f32x4){0.f, 0.f, 0.f, 0.f};

    const int NT = K >> 6;

    auto STAGE = [&](int t, int b) {
        const size_t kk = (size_t)t * 64 + kswz;
        u16* da = sdst + b * 32768;
        #pragma unroll
        for (int u = 0; u < 4; u++) {
            GLOAD16(Ab + (size_t)(u * 64 + rowoff) * lda + kk, da + u * 4096);
            GLOAD16(Bb + (size_t)(u * 64 + rowoff) * ldb + kk, da + 16384 + u * 4096);
        }
    };

    STAGE(0, 0);

    const int larow = (wm << 7) + (lane & 15);
    const int lbrow = (wn << 6) + (lane & 15);
    const int kx    = (((lane >> 4) << 4) ^ ((lane & 7) << 4));    // byte offset, ks=0 (swizzled)

    for (int t = 0; t < NT; ++t) {
        const int cur = t & 1;
        if (t + 1 < NT) {
            STAGE(t + 1, cur ^ 1);
            asm volatile("s_waitcnt vmcnt(8)" ::: "memory");   // tile t landed; t+1's 8 stay in flight
        } else {
            asm volatile("s_waitcnt vmcnt(0)" ::: "memory");
        }
        __builtin_amdgcn_s_barrier();
        asm volatile("" ::: "memory");

        const char* LA = (const char*)(lds + cur * 32768);
        const char* LB = LA + 32768;
        #pragma unroll
        for (int ks = 0; ks < 2; ks++) {
            const int ko = (ks << 6) ^ kx;
            bf16x8 bfr[4];
            #pragma unroll
            for (int nf = 0; nf < 4; nf++)
                bfr[nf] = *(const bf16x8*)(LB + (size_t)(lbrow + (nf << 4)) * 128 + ko);
            #pragma unroll
            for (int ms = 0; ms < 2; ms++) {
                bf16x8 af[4];
                #pragma unroll
                for (int i = 0; i < 4; i++)
                    af[i] = *(const bf16x8*)(LA + (size_t)(larow + (ms << 6) + (i << 4)) * 128 + ko);
                __builtin_amdgcn_s_setprio(1);
                #pragma unroll
                for (int i = 0; i < 4; i++)
                    #pragma unroll
                    for (int nf = 0; nf < 4; nf++)
                        acc[(ms << 2) + i][nf] = __builtin_amdgcn_mfma_f32_16x16x32_bf16(
                            af[i], bfr[nf], acc[(ms << 2) + i][nf], 0, 0, 0);
                __builtin_amdgcn_s_setprio(0);
            }
        }
        __builtin_amdgcn_s_barrier();
        asm volatile("" ::: "memory");
    }

    // epilogue: C/D layout col=lane&15, row=(lane>>4)*4+j
    const int r0 = (lane >> 4) << 2;
    const int c0 = lane & 15;

    if constexpr (EPI == GE_F32) {
        float* Cb = (float*)Cv;
        #pragma unroll
        for (int mf = 0; mf < 8; mf++) {
            int gmb = m0 + (wm << 7) + (mf << 4) + r0;
            #pragma unroll
            for (int j = 0; j < 4; j++) {
                float* crow = Cb + (size_t)(gmb + j) * ldc;
                #pragma unroll
                for (int nf = 0; nf < 4; nf++)
                    crow[n0 + (wn << 6) + (nf << 4) + c0] = acc[mf][nf][j];
            }
        }
    } else if constexpr (EPI == GE_ADDH) {
        float* Cb = (float*)Cv;
        #pragma unroll
        for (int mf = 0; mf < 8; mf++) {
            int gmb = m0 + (wm << 7) + (mf << 4) + r0;
            #pragma unroll
            for (int j = 0; j < 4; j++) {
                float* crow = Cb + (size_t)(gmb + j) * ldc;
                #pragma unroll
                for (int nf = 0; nf < 4; nf++) {
                    int gn = n0 + (wn << 6) + (nf << 4) + c0;
                    crow[gn] = crow[gn] + acc[mf][nf][j] + bias[gn];
                }
            }
        }
    } else if constexpr (EPI == GE_RELU) {
        const bool aregion = (n0 < cE);
        #pragma unroll
        for (int mf = 0; mf < 8; mf++) {
            const int gmb = m0 + (wm << 7) + (mf << 4) + r0;
            const int zz = gmb >> 10, cm = gmb & 1023;
            #pragma unroll
            for (int nf = 0; nf < 4; nf++) {
                const int gn = n0 + (wn << 6) + (nf << 4) + c0;
                const float bv = bias[gn];
                u16 rb[4];
                #pragma unroll
                for (int j = 0; j < 4; j++) {
                    float tv = acc[mf][nf][j] + bv;
                    tv = fmaxf(tv, 0.f);
                    rb[j] = f2bf(tv * tv);
                }
                if (aregion) {
                    #pragma unroll
                    for (int j = 0; j < 4; j++)
                        p0[(size_t)(gmb + j) * cE + gn] = rb[j];
                    uint32_t lo = rb[0] | ((uint32_t)rb[1] << 16);
                    uint32_t hi = rb[2] | ((uint32_t)rb[3] << 16);
                    *(uint2*)&p1[(size_t)zz * (cE * cTL) + (size_t)gn * cTL + cm] = make_uint2(lo, hi);
                } else {
                    #pragma unroll
                    for (int j = 0; j < 4; j++)
                        p2[(size_t)(gmb + j) * cPIN + (gn - cE)] = rb[j];
                }
            }
        }
    }
}

// ---------------------------------------------------------------- bf16 MFMA GEMM (m97 structure, 128x128) for cs/anT
template <int EPI>
__global__ __launch_bounds__(256) void gemm_bt(
        const u16* __restrict__ A, int lda, size_t sA,
        const u16* __restrict__ B, int ldb, size_t sB,
        void* __restrict__ Cv, int ldc, size_t sC, int K,
        const float* __restrict__ invn,
        const float* __restrict__ sp,
        int kcap)
{
    const int n0 = blockIdx.x << 7, m0 = blockIdx.y << 7, z = blockIdx.z;
    const int tid = threadIdx.x, lane = tid & 63, w = tid >> 6;
    const int wr = w >> 1, wc = w & 1;

    if constexpr (EPI == GE_CS) {
        if (n0 > m0) return;   // strictly-upper blocks never read downstream (K-capped consumer)
    }

    const int Keff = kcap ? ((K < n0 + 128) ? K : n0 + 128) : K;

    __shared__ __align__(16) u16 As[128 * 32];
    __shared__ __align__(16) u16 Bs[128 * 32];

    const u16* Ab = A + (size_t)z * sA + (size_t)m0 * lda;
    const u16* Bb = B + (size_t)z * sB + (size_t)n0 * ldb;

    const int srow = (w << 5) + (lane >> 2);
    const int skof = (lane & 3) << 3;
    const u16* ga0 = Ab + (size_t)srow * lda + skof;
    const u16* gb0 = Bb + (size_t)srow * ldb + skof;
    u16* la0 = As + (w << 10);
    u16* lb0 = Bs + (w << 10);

    f32x4 acc[4][4];
    #pragma unroll
    for (int m = 0; m < 4; m++)
        #pragma unroll
        for (int n = 0; n < 4; n++)
            acc[m][n] = (f32x4){0.f, 0.f, 0.f, 0.f};

    const int arow = (wr << 6) + (lane & 15);
    const int brow = (wc << 6) + (lane & 15);
    const int koff = (lane >> 4) << 3;

    for (int kt = 0; kt < Keff; kt += 32) {
        GLOAD16(ga0 + kt, la0);
        GLOAD16(ga0 + kt + (size_t)16 * lda, la0 + 512);
        GLOAD16(gb0 + kt, lb0);
        GLOAD16(gb0 + kt + (size_t)16 * ldb, lb0 + 512);
        __syncthreads();
        bf16x8 af[4], bfr[4];
        #pragma unroll
        for (int m = 0; m < 4; m++)
            af[m] = *(const bf16x8*)&As[(arow + (m << 4)) * 32 + koff];
        #pragma unroll
        for (int n = 0; n < 4; n++)
            bfr[n] = *(const bf16x8*)&Bs[(brow + (n << 4)) * 32 + koff];
        #pragma unroll
        for (int m = 0; m < 4; m++)
            #pragma unroll
            for (int n = 0; n < 4; n++)
                acc[m][n] = __builtin_amdgcn_mfma_f32_16x16x32_bf16(af[m], bfr[n], acc[m][n], 0, 0, 0);
        __syncthreads();
    }

    const int r0 = (lane >> 4) << 2;
    const int c0 = lane & 15;

    if constexpr (EPI == GE_BF16) {
        u16* Cb = (u16*)Cv + (size_t)z * sC;
        #pragma unroll
        for (int m = 0; m < 4; m++) {
            int gmb = m0 + (wr << 6) + (m << 4) + r0;
            #pragma unroll
            for (int j = 0; j < 4; j++) {
                u16* crow = Cb + (size_t)(gmb + j) * ldc;
                #pragma unroll
                for (int n = 0; n < 4; n++)
                    crow[n0 + (wc << 6) + (n << 4) + c0] = f2bf(acc[m][n][j]);
            }
        }
    } else if constexpr (EPI == GE_CS) {
        u16* Cb = (u16*)Cv + (size_t)z * sC;
        const float* invz = invn + (z << 10);
        float inn[4];
        #pragma unroll
        for (int n = 0; n < 4; n++)
            inn[n] = invz[n0 + (wc << 6) + (n << 4) + c0];
        #pragma unroll
        for (int m = 0; m < 4; m++) {
            int gmb = m0 + (wr << 6) + (m << 4) + r0;
            #pragma unroll
            for (int j = 0; j < 4; j++) {
                int gm = gmb + j;
                float im = invz[gm];
                const float* spr = sp + (size_t)gm * cTL;
                u16* crow = Cb + (size_t)gm * ldc;
                #pragma unroll
                for (int n = 0; n < 4; n++) {
                    int gn = n0 + (wc << 6) + (n << 4) + c0;
                    float v = (gn <= gm) ? acc[m][n][j] * im * inn[n] * spr[gn] : 0.f;
                    crow[gn] = f2bf(v);
                }
            }
        }
    }
}

// ---------------------------------------------------------------- launch
extern "C" void kernel_launch(void* const* d_in, const int* in_sizes, int n_in,
                              void* d_out, int out_size, void* d_ws, size_t ws_size,
                              hipStream_t stream) {
    const int*   ids  = (const int*)d_in[0];
    const float* wte  = (const float*)d_in[1];
    const float* rmsw = (const float*)d_in[2];
    const float* enrw = (const float*)d_in[3];
    const float* enrb = (const float*)d_in[4];
    const float* sp   = (const float*)d_in[5];
    const float* fusw = (const float*)d_in[6];
    const float* fusb = (const float*)d_in[7];
    const float* lnfw = (const float*)d_in[8];
    float* out = (float*)d_out;

    // fp32 workspace
    float* ws   = (float*)d_ws;
    float* x    = ws;                      // 3,145,728
    float* xnt  = x    + 3145728;          // 3,145,728
    float* h    = xnt  + 3145728;          // 12,582,912
    float* invn = h    + 12582912;         // 16,384
    float* part = invn + 16384;            // 256
    float* swv  = part + 256;              // 64
    int*   sidx = (int*)(swv + 64);        // 64
    // bf16 workspace
    u16* wteb  = (u16*)(sidx + 64);        // 24,576,000
    u16* enrwb = wteb  + 24576000;         //  9,437,184
    u16* fuswb = enrwb + 9437184;          //  7,077,888
    u16* xnb   = fuswb + 7077888;          // 12,582,912 (reused as finn bf16)
    u16* abuf  = xnb   + 12582912;         // 12,582,912
    u16* aTb   = abuf  + 12582912;         // 12,582,912
    u16* fi    = aTb   + 12582912;         // 37,748,736
    u16* csb   = fi    + 37748736;         // 16,777,216
    u16* anT   = csb   + 16777216;         // 12,582,912
    u16* finnb = xnb;

    // 0. weight conversion fp32->bf16
    cvt_k<<<24576000 / 1024, 256, 0, stream>>>(wte,  wteb,  24576000);
    cvt_k<<< 9437184 / 1024, 256, 0, stream>>>(enrw, enrwb,  9437184);
    cvt_k<<< 7077888 / 1024, 256, 0, stream>>>(fusw, fuswb,  7077888);

    // 1. embed + token normalize (fp32)
    embed_k<<<cB * cT, 256, 0, stream>>>(ids, wte, x, xnt);
    // 2. retrieval scores + top-k + assembly (fp32, deterministic)
    pair_scores_k<<<dim3(4, 56), 256, 0, stream>>>(xnt, part);
    score_topk_k<<<1, 64, 0, stream>>>(part, sidx, swv);
    build_k<<<dim3(cNCH, cTL), 192, 0, stream>>>(x, sidx, swv, h);

    // 3. layers
    for (int l = 0; l < cL; l++) {
        rmsnorm_bf_k<<<cMR, 256, 0, stream>>>(h, rmsw + (size_t)l * cE, xnb);
        // xp = relu(xn @ enr_w.T + b)^2 ; writes a (row-major + transposed) and b/x1 into fi
        gemm256<GE_RELU><<<dim3(cED / 256, cMR / 256), 512, 0, stream>>>(
            xnb, cE, enrwb + (size_t)l * cED * cE, cE,
            nullptr, 0, cE, enrb + (size_t)l * cED,
            abuf, aTb, fi, 3);
        invna_bf_k<<<cMR, 256, 0, stream>>>(abuf, invn);
        // M = tril(sp) * cosine(a,a)
        gemm_bt<GE_CS><<<dim3(8, 8, cNCH), 256, 0, stream>>>(
            abuf, cE, (size_t)cTL * cE, abuf, cE, (size_t)cTL * cE,
            csb, cTL, (size_t)cTL * cTL, cE,
            invn, sp + (size_t)l * cTL * cTL, 0);
        // a_newT[e][m] = sum_c aT[e][c] * M[m][c]  (K capped at n0+128 by tril)
        gemm_bt<GE_BF16><<<dim3(8, 6, cNCH), 256, 0, stream>>>(
            aTb, cTL, (size_t)cE * cTL, csb, cTL, (size_t)cTL * cTL,
            anT, cTL, (size_t)cE * cTL, cTL,
            nullptr, nullptr, 1);
        // fi[:, :768] = a_new * b (transpose + elementwise)
        tmul_k<<<dim3(16, 12, cNCH), 256, 0, stream>>>(anT, fi);
        // h += fi @ fus_w.T + fus_b
        gemm256<GE_ADDH><<<dim3(cE / 256, cMR / 256), 512, 0, stream>>>(
            fi, cPIN, fuswb + (size_t)l * cE * cPIN, cPIN,
            h, cE, cPIN, fusb + (size_t)l * cE,
            nullptr, nullptr, nullptr, 3);
    }

    // 4. final norm + logits
    final_bf_k<<<cB * cT, 256, 0, stream>>>(h, lnfw, finnb);
    gemm256<GE_F32><<<dim3(cV / 256, (cB * cT) / 256), 512, 0, stream>>>(
        finnb, cE, wteb, cE, out, cV, cE,
        nullptr, nullptr, nullptr, nullptr, 3);
}

// Round 5
// 1865.670 us; speedup vs baseline: 5.7298x; 1.0274x over previous
//
#include <hip/hip_runtime.h>
#include <math.h>

typedef unsigned short u16;
typedef __attribute__((ext_vector_type(8))) short bf16x8;
typedef __attribute__((ext_vector_type(4))) float f32x4;

// Problem constants
constexpr int cV = 32000, cE = 768, cL = 4, cC = 256, cTL = 1024;
constexpr int cED = 3072, cPIN = 2304;
constexpr int cB = 2, cT = 2048, cN = 8, cNCH = 16, cMR = 16384;

// ---------------------------------------------------------------- bf16 helpers
__device__ inline float bf2f(u16 u) {
    union { uint32_t i; float f; } v; v.i = ((uint32_t)u) << 16; return v.f;
}
__device__ inline u16 f2bf(float f) {
    union { float f; uint32_t u; } v; v.f = f;
    uint32_t r = v.u + 0x7FFF + ((v.u >> 16) & 1);
    return (u16)(r >> 16);
}

// async global->LDS, 16B per lane; LDS dest is wave-uniform base + lane*16
#define GLOAD16(gp, lp) __builtin_amdgcn_global_load_lds( \
    (const __attribute__((address_space(1))) void*)(gp), \
    (__attribute__((address_space(3))) void*)(lp), 16, 0, 0)

// ---------------------------------------------------------------- reductions
__device__ inline float blockReduceSum256(float v, float* sbuf) {
    #pragma unroll
    for (int m = 1; m < 64; m <<= 1) v += __shfl_xor(v, m, 64);
    int lane = threadIdx.x & 63, w = threadIdx.x >> 6;
    if (lane == 0) sbuf[w] = v;
    __syncthreads();
    return sbuf[0] + sbuf[1] + sbuf[2] + sbuf[3];
}

// ---------------------------------------------------------------- fp32 -> bf16 bulk convert
__global__ __launch_bounds__(256) void cvt_k(const float* __restrict__ in,
                                             u16* __restrict__ out, long n) {
    long i = ((long)blockIdx.x * 256 + threadIdx.x) * 4;
    if (i >= n) return;
    float4 v = *(const float4*)(in + i);
    uint32_t lo = f2bf(v.x) | ((uint32_t)f2bf(v.y) << 16);
    uint32_t hi = f2bf(v.z) | ((uint32_t)f2bf(v.w) << 16);
    *(uint2*)(out + i) = make_uint2(lo, hi);
}

// ---------------------------------------------------------------- embed + token-normalize (fp32, feeds topk)
__global__ __launch_bounds__(256) void embed_k(const int* __restrict__ ids,
                                               const float* __restrict__ wte,
                                               float* __restrict__ x,
                                               float* __restrict__ xnt) {
    __shared__ float sb[4];
    int tok = blockIdx.x;
    const float* src = wte + (size_t)ids[tok] * cE;
    int t = threadIdx.x;
    float v0 = src[t], v1 = src[t + 256], v2 = src[t + 512];
    float tot = blockReduceSum256(v0 * v0 + v1 * v1 + v2 * v2, sb);
    float inv = 1.0f / (sqrtf(tot) + 1e-8f);
    size_t o = (size_t)tok * cE + t;
    x[o] = v0; x[o + 256] = v1; x[o + 512] = v2;
    xnt[o] = v0 * inv; xnt[o + 256] = v1 * inv; xnt[o + 512] = v2 * inv;
}

// ---------------------------------------------------------------- rmsnorm -> bf16
__global__ __launch_bounds__(256) void rmsnorm_bf_k(const float* __restrict__ in,
                                                    const float* __restrict__ w,
                                                    u16* __restrict__ out) {
    __shared__ float sb[4];
    size_t row = blockIdx.x;
    const float* src = in + row * cE;
    int t = threadIdx.x;
    float v0 = src[t], v1 = src[t + 256], v2 = src[t + 512];
    float tot = blockReduceSum256(v0 * v0 + v1 * v1 + v2 * v2, sb);
    float s = 1.0f / sqrtf(tot * (1.0f / cE) + 1e-10f);
    out[row * cE + t]       = f2bf(v0 * s * w[t]);
    out[row * cE + t + 256] = f2bf(v1 * s * w[t + 256]);
    out[row * cE + t + 512] = f2bf(v2 * s * w[t + 512]);
}

// ---------------------------------------------------------------- inverse row norm of a (bf16 input)
__global__ __launch_bounds__(256) void invna_bf_k(const u16* __restrict__ a,
                                                  float* __restrict__ invna) {
    __shared__ float sb[4];
    size_t row = blockIdx.x;
    const u16* src = a + row * cE;
    int t = threadIdx.x;
    float v0 = bf2f(src[t]), v1 = bf2f(src[t + 256]), v2 = bf2f(src[t + 512]);
    float tot = blockReduceSum256(v0 * v0 + v1 * v1 + v2 * v2, sb);
    if (t == 0) invna[row] = 1.0f / sqrtf(tot + 1e-8f);
}

// ---------------------------------------------------------------- final row extract + rmsnorm(lnf) -> bf16
__global__ __launch_bounds__(256) void final_bf_k(const float* __restrict__ h,
                                                  const float* __restrict__ lnf,
                                                  u16* __restrict__ finn) {
    __shared__ float sb[4];
    int tok = blockIdx.x;
    int b = tok >> 11, tt = tok & 2047;
    int i = tt >> 8, c = tt & 255;
    size_t row = (size_t)(b * cN + i) * cTL + (cTL - cC) + c;
    const float* src = h + row * cE;
    int t = threadIdx.x;
    float v0 = src[t], v1 = src[t + 256], v2 = src[t + 512];
    float tot = blockReduceSum256(v0 * v0 + v1 * v1 + v2 * v2, sb);
    float s = 1.0f / sqrtf(tot * (1.0f / cE) + 1e-10f);
    size_t o = (size_t)tok * cE + t;
    finn[o]       = f2bf(v0 * s * lnf[t]);
    finn[o + 256] = f2bf(v1 * s * lnf[t + 256]);
    finn[o + 512] = f2bf(v2 * s * lnf[t + 512]);
}

// ---------------------------------------------------------------- pair scores v2 (fp32, deterministic)
__global__ __launch_bounds__(256) void pair_scores_k(const float* __restrict__ xnt,
                                                     float* __restrict__ partial) {
    __shared__ float As[16][64];
    __shared__ float Bs[4][16][64];
    __shared__ float rowmax[4][64];
    int ct = blockIdx.x;
    int p  = blockIdx.y;
    int b = p / 28, pp = p % 28;
    int i = 1; while (pp >= i) { pp -= i; i++; }
    int j = pp;
    const float* Abase = xnt + ((size_t)(b * cT) + i * cC + ct * 64) * cE;
    const float* Bbase = xnt + ((size_t)(b * cT) + j * cC) * cE;
    int tid = threadIdx.x, lane = tid & 63, w = tid >> 6;
    int ly = lane >> 3, lx = lane & 7;
    int srow = tid >> 2, skc = (tid & 3) << 2;
    const float* bw = Bbase + (size_t)(w * 64) * cE;

    float acc[8][8];
    #pragma unroll
    for (int a2 = 0; a2 < 8; a2++)
        #pragma unroll
        for (int b2 = 0; b2 < 8; b2++) acc[a2][b2] = 0.f;

    for (int k0 = 0; k0 < cE; k0 += 16) {
        float4 va = *(const float4*)(Abase + (size_t)srow * cE + k0 + skc);
        As[skc + 0][srow] = va.x; As[skc + 1][srow] = va.y;
        As[skc + 2][srow] = va.z; As[skc + 3][srow] = va.w;
        #pragma unroll
        for (int q = 0; q < 4; q++) {
            int id = (q << 6) + lane;
            int br = id >> 2, bkc = (id & 3) << 2;
            float4 vb = *(const float4*)(bw + (size_t)br * cE + k0 + bkc);
            Bs[w][bkc + 0][br] = vb.x; Bs[w][bkc + 1][br] = vb.y;
            Bs[w][bkc + 2][br] = vb.z; Bs[w][bkc + 3][br] = vb.w;
        }
        __syncthreads();
        #pragma unroll
        for (int k = 0; k < 16; k++) {
            float av[8], bv[8];
            *(float4*)&av[0] = *(float4*)&As[k][ly << 3];
            *(float4*)&av[4] = *(float4*)&As[k][(ly << 3) + 4];
            *(float4*)&bv[0] = *(float4*)&Bs[w][k][lx << 3];
            *(float4*)&bv[4] = *(float4*)&Bs[w][k][(lx << 3) + 4];
            #pragma unroll
            for (int r = 0; r < 8; r++)
                #pragma unroll
                for (int q = 0; q < 8; q++)
                    acc[r][q] = fmaf(av[r], bv[q], acc[r][q]);
        }
        __syncthreads();
    }
    #pragma unroll
    for (int r = 0; r < 8; r++) {
        float m = acc[r][0];
        #pragma unroll
        for (int q = 1; q < 8; q++) m = fmaxf(m, acc[r][q]);
        m = fmaxf(m, __shfl_xor(m, 1, 64));
        m = fmaxf(m, __shfl_xor(m, 2, 64));
        m = fmaxf(m, __shfl_xor(m, 4, 64));
        if (lx == 0) rowmax[w][(ly << 3) + r] = m;
    }
    __syncthreads();
    if (tid == 0) {
        float s = 0.f;
        for (int r = 0; r < 64; r++)
            s += fmaxf(fmaxf(rowmax[0][r], rowmax[1][r]),
                       fmaxf(rowmax[2][r], rowmax[3][r]));
        partial[p * 4 + ct] = s;
    }
}

// ---------------------------------------------------------------- top-k + sort + weights (unchanged)
__global__ void score_topk_k(const float* __restrict__ partial,
                             int* __restrict__ sidx, float* __restrict__ sw) {
    __shared__ float sc[2][8][8];
    int t = threadIdx.x;
    if (t < 56) {
        int b = t / 28, pp = t % 28;
        int i = 1; while (pp >= i) { pp -= i; i++; }
        int j = pp;
        sc[b][i][j] = partial[t * 4 + 0] + partial[t * 4 + 1] + partial[t * 4 + 2] + partial[t * 4 + 3];
    }
    __syncthreads();
    if (t < 16) {
        int b = t >> 3, i = t & 7;
        int nsel = i < 3 ? i : 3;
        if (nsel > 0) {
            float loc[7];
            for (int j2 = 0; j2 < i; j2++) loc[j2] = sc[b][i][j2];
            int idxs[3]; float vals[3];
            for (int s = 0; s < nsel; s++) {
                int am = 0; float mv = loc[0];
                for (int j2 = 1; j2 < i; j2++) if (loc[j2] > mv) { mv = loc[j2]; am = j2; }
                idxs[s] = am; vals[s] = mv; loc[am] = -1e30f;
            }
            for (int a = 0; a < nsel; a++)
                for (int c2 = a + 1; c2 < nsel; c2++)
                    if (idxs[c2] < idxs[a]) {
                        int ti = idxs[a]; idxs[a] = idxs[c2]; idxs[c2] = ti;
                        float tv = vals[a]; vals[a] = vals[c2]; vals[c2] = tv;
                    }
            float den = vals[0] + 1e-8f;
            for (int s = 0; s < nsel; s++) {
                sidx[(b * 8 + i) * 3 + s] = idxs[s];
                sw[(b * 8 + i) * 3 + s]   = vals[s] / den;
            }
        }
    }
}

// ---------------------------------------------------------------- assemble extended context h (fp32)
__global__ __launch_bounds__(192) void build_k(const float* __restrict__ x,
                                               const int* __restrict__ sidx,
                                               const float* __restrict__ sw,
                                               float* __restrict__ h) {
    int m = blockIdx.x, r = blockIdx.y;
    int b = m >> 3, i = m & 7;
    int nsel = i < 3 ? i : 3;
    int pad = cTL - (nsel + 1) * cC;
    int pos = r - pad;
    float4 val = make_float4(0.f, 0.f, 0.f, 0.f);
    if (pos >= 0) {
        if (pos < nsel * cC) {
            int s = pos >> 8;
            int jj = sidx[(b * 8 + i) * 3 + s];
            float wg = sw[(b * 8 + i) * 3 + s];
            const float4* src = (const float4*)(x + ((size_t)(b * cT) + jj * cC + (pos & 255)) * cE);
            float4 v = src[threadIdx.x];
            val = make_float4(v.x * wg, v.y * wg, v.z * wg, v.w * wg);
        } else {
            int c = pos - nsel * cC;
            const float4* src = (const float4*)(x + ((size_t)(b * cT) + i * cC + c) * cE);
            val = src[threadIdx.x];
        }
    }
    ((float4*)(h + ((size_t)m * cTL + r) * cE))[threadIdx.x] = val;
}

// ---------------------------------------------------------------- transpose(a_newT) * fi[:, :768] -> fi[:, :768]
__global__ __launch_bounds__(256) void tmul_k(const u16* __restrict__ anT,
                                              u16* __restrict__ fi) {
    __shared__ u16 tile[64][65];
    int c0 = blockIdx.x << 6, j0 = blockIdx.y << 6, z = blockIdx.z;
    const u16* src = anT + (size_t)z * (cE * cTL);
    int t = threadIdx.x;
    #pragma unroll
    for (int it = 0; it < 16; it++) {
        int id = t + (it << 8);
        int r = id >> 6, c = id & 63;
        tile[r][c] = src[(size_t)(j0 + r) * cTL + c0 + c];
    }
    __syncthreads();
    #pragma unroll
    for (int it = 0; it < 16; it++) {
        int id = t + (it << 8);
        int cm = id >> 6, jj = id & 63;
        size_t o = (size_t)(z * cTL + c0 + cm) * cPIN + j0 + jj;
        fi[o] = f2bf(bf2f(tile[jj][cm]) * bf2f(fi[o]));
    }
}

enum { GE_F32 = 0, GE_RELU = 1, GE_CS = 2, GE_ADDH = 3, GE_BF16 = 4 };

// ---------------------------------------------------------------- 256x256 pipelined MFMA GEMM
// NT layout: C[m,n] = sum_k A[m*lda+k] * B[n*ldb+k].
// BK=32, ring of 4 LDS slots (A 16KB + B 16KB each), 8 waves (2M x 4N).
// Iteration t: phase1 {read B + A-rows0-63, stage A of t+3, bar, 16 MFMA, bar}
//              phase2 {read A-rows64-127,  stage B of t+3, vmcnt(8), bar, 16 MFMA, bar}
// vmcnt(8) = tiles t+2,t+3 in flight (4 loads each); tile t+1 guaranteed landed.
// Swizzle: LDS 16B-chunk c = q ^ ((row>>1)&3), applied to gload SOURCE and ds_read addr.
template <int EPI>
__global__ __launch_bounds__(512, 2) void gemm256(
        const u16* __restrict__ A, int lda,
        const u16* __restrict__ B, int ldb,
        void* __restrict__ Cv, int ldc, int K,
        const float* __restrict__ bias,
        u16* __restrict__ p0, u16* __restrict__ p1, u16* __restrict__ p2,
        int swz)
{
    __shared__ __align__(16) u16 lds[65536];   // 4 slots x 16384 u16 (A:8192, B:8192)
    int bx = blockIdx.x, by = blockIdx.y;
    if (swz == 3) {   // XCD owns gy/8 m-tiles; all XCDs sweep n in sync
        int gx = gridDim.x, gy = gridDim.y;
        int orig = by * gx + bx;
        int mpx = gy >> 3;
        int xcd = orig & 7, idx = orig >> 3;
        by = xcd * mpx + idx % mpx;
        bx = idx / mpx;
        (void)gx;
    }
    const int n0 = bx << 8, m0 = by << 8;
    const int tid = threadIdx.x, lane = tid & 63, w = tid >> 6;
    const int wm = w >> 2, wn = w & 3;

    const u16* Ab = A + (size_t)m0 * lda;
    const u16* Bb = B + (size_t)n0 * ldb;

    // staging geometry: thread tid owns LDS linear chunk tid (16B) in each 8KB round
    const int srow = tid >> 2;                         // rows 0..127 (round u adds 128)
    const int sq   = (tid & 3) ^ ((srow >> 1) & 3);    // pre-swizzled global 16B-chunk
    u16* ldst = lds + (size_t)tid * 8;                 // + slot*16384 (+4096 round1, +8192 B)

    f32x4 acc[8][4];
    #pragma unroll
    for (int m = 0; m < 8; m++)
        #pragma unroll
        for (int n = 0; n < 4; n++) acc[m][n] = (f32x4){0.f, 0.f, 0.f, 0.f};

    const int NT = K >> 5;

    auto STAGE_A = [&](int tt) {
        const u16* src = Ab + (size_t)tt * 32 + (size_t)sq * 8;
        u16* d = ldst + ((tt & 3) << 14);
        GLOAD16(src + (size_t)srow * lda,         d);
        GLOAD16(src + (size_t)(srow + 128) * lda, d + 4096);
    };
    auto STAGE_B = [&](int tt) {
        const u16* src = Bb + (size_t)tt * 32 + (size_t)sq * 8;
        u16* d = ldst + ((tt & 3) << 14) + 8192;
        GLOAD16(src + (size_t)srow * ldb,         d);
        GLOAD16(src + (size_t)(srow + 128) * ldb, d + 4096);
    };

    // read-fragment constants: row = base16 + l15; chunk = (lane>>4) ^ ((l15>>1)&3)
    const int l15 = lane & 15;
    const int ck  = (((lane >> 4) ^ ((l15 >> 1) & 3)) << 3);   // u16 offset within row

    // prologue: stage tiles 0,1,2 ; wait until tile 0 landed (8 newest may remain)
    STAGE_A(0); STAGE_B(0);
    STAGE_A(1); STAGE_B(1);
    STAGE_A(2); STAGE_B(2);
    asm volatile("s_waitcnt vmcnt(8)" ::: "memory");
    __builtin_amdgcn_s_barrier();

    for (int t = 0; t < NT; ++t) {
        const u16* S  = lds + ((t & 3) << 14);
        const u16* SB = S + 8192;
        bf16x8 bfr[4], af[4];
        // ---- phase 1: B frags + A rows 0-63 of this wave's half
        #pragma unroll
        for (int nf = 0; nf < 4; nf++)
            bfr[nf] = *(const bf16x8*)(SB + (size_t)((wn << 6) + (nf << 4) + l15) * 32 + ck);
        #pragma unroll
        for (int i = 0; i < 4; i++)
            af[i] = *(const bf16x8*)(S + (size_t)((wm << 7) + (i << 4) + l15) * 32 + ck);
        if (t + 3 < NT) STAGE_A(t + 3);
        __builtin_amdgcn_s_barrier();
        __builtin_amdgcn_s_setprio(1);
        #pragma unroll
        for (int i = 0; i < 4; i++)
            #pragma unroll
            for (int nf = 0; nf < 4; nf++)
                acc[i][nf] = __builtin_amdgcn_mfma_f32_16x16x32_bf16(af[i], bfr[nf], acc[i][nf], 0, 0, 0);
        __builtin_amdgcn_s_setprio(0);
        __builtin_amdgcn_s_barrier();
        // ---- phase 2: A rows 64-127
        #pragma unroll
        for (int i = 0; i < 4; i++)
            af[i] = *(const bf16x8*)(S + (size_t)((wm << 7) + 64 + (i << 4) + l15) * 32 + ck);
        if (t + 3 < NT) STAGE_B(t + 3);
        asm volatile("s_waitcnt vmcnt(8)" ::: "memory");
        __builtin_amdgcn_s_barrier();
        __builtin_amdgcn_s_setprio(1);
        #pragma unroll
        for (int i = 0; i < 4; i++)
            #pragma unroll
            for (int nf = 0; nf < 4; nf++)
                acc[4 + i][nf] = __builtin_amdgcn_mfma_f32_16x16x32_bf16(af[i], bfr[nf], acc[4 + i][nf], 0, 0, 0);
        __builtin_amdgcn_s_setprio(0);
        __builtin_amdgcn_s_barrier();
    }

    // epilogue: C/D layout col=lane&15, row=(lane>>4)*4+j
    const int r0 = (lane >> 4) << 2;
    const int c0 = lane & 15;

    if constexpr (EPI == GE_F32) {
        float* Cb = (float*)Cv;
        #pragma unroll
        for (int mf = 0; mf < 8; mf++) {
            int gmb = m0 + (wm << 7) + (mf << 4) + r0;
            #pragma unroll
            for (int j = 0; j < 4; j++) {
                float* crow = Cb + (size_t)(gmb + j) * ldc;
                #pragma unroll
                for (int nf = 0; nf < 4; nf++)
                    crow[n0 + (wn << 6) + (nf << 4) + c0] = acc[mf][nf][j];
            }
        }
    } else if constexpr (EPI == GE_ADDH) {
        float* Cb = (float*)Cv;
        #pragma unroll
        for (int mf = 0; mf < 8; mf++) {
            int gmb = m0 + (wm << 7) + (mf << 4) + r0;
            #pragma unroll
            for (int j = 0; j < 4; j++) {
                float* crow = Cb + (size_t)(gmb + j) * ldc;
                #pragma unroll
                for (int nf = 0; nf < 4; nf++) {
                    int gn = n0 + (wn << 6) + (nf << 4) + c0;
                    crow[gn] = crow[gn] + acc[mf][nf][j] + bias[gn];
                }
            }
        }
    } else if constexpr (EPI == GE_RELU) {
        const bool aregion = (n0 < cE);
        #pragma unroll
        for (int mf = 0; mf < 8; mf++) {
            const int gmb = m0 + (wm << 7) + (mf << 4) + r0;
            const int zz = gmb >> 10, cm = gmb & 1023;
            #pragma unroll
            for (int nf = 0; nf < 4; nf++) {
                const int gn = n0 + (wn << 6) + (nf << 4) + c0;
                const float bv = bias[gn];
                u16 rb[4];
                #pragma unroll
                for (int j = 0; j < 4; j++) {
                    float tv = acc[mf][nf][j] + bv;
                    tv = fmaxf(tv, 0.f);
                    rb[j] = f2bf(tv * tv);
                }
                if (aregion) {
                    #pragma unroll
                    for (int j = 0; j < 4; j++)
                        p0[(size_t)(gmb + j) * cE + gn] = rb[j];
                    uint32_t lo = rb[0] | ((uint32_t)rb[1] << 16);
                    uint32_t hi = rb[2] | ((uint32_t)rb[3] << 16);
                    *(uint2*)&p1[(size_t)zz * (cE * cTL) + (size_t)gn * cTL + cm] = make_uint2(lo, hi);
                } else {
                    #pragma unroll
                    for (int j = 0; j < 4; j++)
                        p2[(size_t)(gmb + j) * cPIN + (gn - cE)] = rb[j];
                }
            }
        }
    }
}

// ---------------------------------------------------------------- bf16 MFMA GEMM (m97 structure, 128x128) for cs/anT
template <int EPI>
__global__ __launch_bounds__(256) void gemm_bt(
        const u16* __restrict__ A, int lda, size_t sA,
        const u16* __restrict__ B, int ldb, size_t sB,
        void* __restrict__ Cv, int ldc, size_t sC, int K,
        const float* __restrict__ invn,
        const float* __restrict__ sp,
        int kcap)
{
    const int n0 = blockIdx.x << 7, m0 = blockIdx.y << 7, z = blockIdx.z;
    const int tid = threadIdx.x, lane = tid & 63, w = tid >> 6;
    const int wr = w >> 1, wc = w & 1;

    if constexpr (EPI == GE_CS) {
        if (n0 > m0) return;   // strictly-upper blocks never read downstream (K-capped consumer)
    }

    const int Keff = kcap ? ((K < n0 + 128) ? K : n0 + 128) : K;

    __shared__ __align__(16) u16 As[128 * 32];
    __shared__ __align__(16) u16 Bs[128 * 32];

    const u16* Ab = A + (size_t)z * sA + (size_t)m0 * lda;
    const u16* Bb = B + (size_t)z * sB + (size_t)n0 * ldb;

    const int srow = (w << 5) + (lane >> 2);
    const int skof = (lane & 3) << 3;
    const u16* ga0 = Ab + (size_t)srow * lda + skof;
    const u16* gb0 = Bb + (size_t)srow * ldb + skof;
    u16* la0 = As + (w << 10);
    u16* lb0 = Bs + (w << 10);

    f32x4 acc[4][4];
    #pragma unroll
    for (int m = 0; m < 4; m++)
        #pragma unroll
        for (int n = 0; n < 4; n++)
            acc[m][n] = (f32x4){0.f, 0.f, 0.f, 0.f};

    const int arow = (wr << 6) + (lane & 15);
    const int brow = (wc << 6) + (lane & 15);
    const int koff = (lane >> 4) << 3;

    for (int kt = 0; kt < Keff; kt += 32) {
        GLOAD16(ga0 + kt, la0);
        GLOAD16(ga0 + kt + (size_t)16 * lda, la0 + 512);
        GLOAD16(gb0 + kt, lb0);
        GLOAD16(gb0 + kt + (size_t)16 * ldb, lb0 + 512);
        __syncthreads();
        bf16x8 af[4], bfr[4];
        #pragma unroll
        for (int m = 0; m < 4; m++)
            af[m] = *(const bf16x8*)&As[(arow + (m << 4)) * 32 + koff];
        #pragma unroll
        for (int n = 0; n < 4; n++)
            bfr[n] = *(const bf16x8*)&Bs[(brow + (n << 4)) * 32 + koff];
        #pragma unroll
        for (int m = 0; m < 4; m++)
            #pragma unroll
            for (int n = 0; n < 4; n++)
                acc[m][n] = __builtin_amdgcn_mfma_f32_16x16x32_bf16(af[m], bfr[n], acc[m][n], 0, 0, 0);
        __syncthreads();
    }

    const int r0 = (lane >> 4) << 2;
    const int c0 = lane & 15;

    if constexpr (EPI == GE_BF16) {
        u16* Cb = (u16*)Cv + (size_t)z * sC;
        #pragma unroll
        for (int m = 0; m < 4; m++) {
            int gmb = m0 + (wr << 6) + (m << 4) + r0;
            #pragma unroll
            for (int j = 0; j < 4; j++) {
                u16* crow = Cb + (size_t)(gmb + j) * ldc;
                #pragma unroll
                for (int n = 0; n < 4; n++)
                    crow[n0 + (wc << 6) + (n << 4) + c0] = f2bf(acc[m][n][j]);
            }
        }
    } else if constexpr (EPI == GE_CS) {
        u16* Cb = (u16*)Cv + (size_t)z * sC;
        const float* invz = invn + (z << 10);
        float inn[4];
        #pragma unroll
        for (int n = 0; n < 4; n++)
            inn[n] = invz[n0 + (wc << 6) + (n << 4) + c0];
        #pragma unroll
        for (int m = 0; m < 4; m++) {
            int gmb = m0 + (wr << 6) + (m << 4) + r0;
            #pragma unroll
            for (int j = 0; j < 4; j++) {
                int gm = gmb + j;
                float im = invz[gm];
                const float* spr = sp + (size_t)gm * cTL;
                u16* crow = Cb + (size_t)gm * ldc;
                #pragma unroll
                for (int n = 0; n < 4; n++) {
                    int gn = n0 + (wc << 6) + (n << 4) + c0;
                    float v = (gn <= gm) ? acc[m][n][j] * im * inn[n] * spr[gn] : 0.f;
                    crow[gn] = f2bf(v);
                }
            }
        }
    }
}

// ---------------------------------------------------------------- launch
extern "C" void kernel_launch(void* const* d_in, const int* in_sizes, int n_in,
                              void* d_out, int out_size, void* d_ws, size_t ws_size,
                              hipStream_t stream) {
    const int*   ids  = (const int*)d_in[0];
    const float* wte  = (const float*)d_in[1];
    const float* rmsw = (const float*)d_in[2];
    const float* enrw = (const float*)d_in[3];
    const float* enrb = (const float*)d_in[4];
    const float* sp   = (const float*)d_in[5];
    const float* fusw = (const float*)d_in[6];
    const float* fusb = (const float*)d_in[7];
    const float* lnfw = (const float*)d_in[8];
    float* out = (float*)d_out;

    // fp32 workspace
    float* ws   = (float*)d_ws;
    float* x    = ws;                      // 3,145,728
    float* xnt  = x    + 3145728;          // 3,145,728
    float* h    = xnt  + 3145728;          // 12,582,912
    float* invn = h    + 12582912;         // 16,384
    float* part = invn + 16384;            // 256
    float* swv  = part + 256;              // 64
    int*   sidx = (int*)(swv + 64);        // 64
    // bf16 workspace
    u16* wteb  = (u16*)(sidx + 64);        // 24,576,000
    u16* enrwb = wteb  + 24576000;         //  9,437,184
    u16* fuswb = enrwb + 9437184;          //  7,077,888
    u16* xnb   = fuswb + 7077888;          // 12,582,912 (reused as finn bf16)
    u16* abuf  = xnb   + 12582912;         // 12,582,912
    u16* aTb   = abuf  + 12582912;         // 12,582,912
    u16* fi    = aTb   + 12582912;         // 37,748,736
    u16* csb   = fi    + 37748736;         // 16,777,216
    u16* anT   = csb   + 16777216;         // 12,582,912
    u16* finnb = xnb;

    // 0. weight conversion fp32->bf16
    cvt_k<<<24576000 / 1024, 256, 0, stream>>>(wte,  wteb,  24576000);
    cvt_k<<< 9437184 / 1024, 256, 0, stream>>>(enrw, enrwb,  9437184);
    cvt_k<<< 7077888 / 1024, 256, 0, stream>>>(fusw, fuswb,  7077888);

    // 1. embed + token normalize (fp32)
    embed_k<<<cB * cT, 256, 0, stream>>>(ids, wte, x, xnt);
    // 2. retrieval scores + top-k + assembly (fp32, deterministic)
    pair_scores_k<<<dim3(4, 56), 256, 0, stream>>>(xnt, part);
    score_topk_k<<<1, 64, 0, stream>>>(part, sidx, swv);
    build_k<<<dim3(cNCH, cTL), 192, 0, stream>>>(x, sidx, swv, h);

    // 3. layers
    for (int l = 0; l < cL; l++) {
        rmsnorm_bf_k<<<cMR, 256, 0, stream>>>(h, rmsw + (size_t)l * cE, xnb);
        // xp = relu(xn @ enr_w.T + b)^2 ; writes a (row-major + transposed) and b/x1 into fi
        gemm256<GE_RELU><<<dim3(cED / 256, cMR / 256), 512, 0, stream>>>(
            xnb, cE, enrwb + (size_t)l * cED * cE, cE,
            nullptr, 0, cE, enrb + (size_t)l * cED,
            abuf, aTb, fi, 3);
        invna_bf_k<<<cMR, 256, 0, stream>>>(abuf, invn);
        // M = tril(sp) * cosine(a,a)
        gemm_bt<GE_CS><<<dim3(8, 8, cNCH), 256, 0, stream>>>(
            abuf, cE, (size_t)cTL * cE, abuf, cE, (size_t)cTL * cE,
            csb, cTL, (size_t)cTL * cTL, cE,
            invn, sp + (size_t)l * cTL * cTL, 0);
        // a_newT[e][m] = sum_c aT[e][c] * M[m][c]  (K capped at n0+128 by tril)
        gemm_bt<GE_BF16><<<dim3(8, 6, cNCH), 256, 0, stream>>>(
            aTb, cTL, (size_t)cE * cTL, csb, cTL, (size_t)cTL * cTL,
            anT, cTL, (size_t)cE * cTL, cTL,
            nullptr, nullptr, 1);
        // fi[:, :768] = a_new * b (transpose + elementwise)
        tmul_k<<<dim3(16, 12, cNCH), 256, 0, stream>>>(anT, fi);
        // h += fi @ fus_w.T + fus_b
        gemm256<GE_ADDH><<<dim3(cE / 256, cMR / 256), 512, 0, stream>>>(
            fi, cPIN, fuswb + (size_t)l * cE * cPIN, cPIN,
            h, cE, cPIN, fusb + (size_t)l * cE,
            nullptr, nullptr, nullptr, 3);
    }

    // 4. final norm + logits
    final_bf_k<<<cB * cT, 256, 0, stream>>>(h, lnfw, finnb);
    gemm256<GE_F32><<<dim3(cV / 256, (cB * cT) / 256), 512, 0, stream>>>(
        finnb, cE, wteb, cE, out, cV, cE,
        nullptr, nullptr, nullptr, nullptr, 3);
}

// Round 6
// 1796.397 us; speedup vs baseline: 5.9507x; 1.0386x over previous
//
#include <hip/hip_runtime.h>
#include <math.h>

typedef unsigned short u16;
typedef __attribute__((ext_vector_type(8))) short bf16x8;
typedef __attribute__((ext_vector_type(4))) float f32x4;

// Problem constants
constexpr int cV = 32000, cE = 768, cL = 4, cC = 256, cTL = 1024;
constexpr int cED = 3072, cPIN = 2304;
constexpr int cB = 2, cT = 2048, cN = 8, cNCH = 16, cMR = 16384;

// ---------------------------------------------------------------- bf16 helpers
__device__ inline float bf2f(u16 u) {
    union { uint32_t i; float f; } v; v.i = ((uint32_t)u) << 16; return v.f;
}
__device__ inline u16 f2bf(float f) {
    union { float f; uint32_t u; } v; v.f = f;
    uint32_t r = v.u + 0x7FFF + ((v.u >> 16) & 1);
    return (u16)(r >> 16);
}

// async global->LDS, 16B per lane; LDS dest is wave-uniform base + lane*16
#define GLOAD16(gp, lp) __builtin_amdgcn_global_load_lds( \
    (const __attribute__((address_space(1))) void*)(gp), \
    (__attribute__((address_space(3))) void*)(lp), 16, 0, 0)

// ---------------------------------------------------------------- reductions
__device__ inline float blockReduceSum256(float v, float* sbuf) {
    #pragma unroll
    for (int m = 1; m < 64; m <<= 1) v += __shfl_xor(v, m, 64);
    int lane = threadIdx.x & 63, w = threadIdx.x >> 6;
    if (lane == 0) sbuf[w] = v;
    __syncthreads();
    return sbuf[0] + sbuf[1] + sbuf[2] + sbuf[3];
}

// ---------------------------------------------------------------- fp32 -> bf16 bulk convert (3 arrays, 1 launch)
__global__ __launch_bounds__(256) void cvt3_k(const float* __restrict__ s0, u16* __restrict__ d0, long n0,
                                              const float* __restrict__ s1, u16* __restrict__ d1, long n1,
                                              const float* __restrict__ s2, u16* __restrict__ d2, long n2) {
    long i = ((long)blockIdx.x * 256 + threadIdx.x) * 4;
    const float* s; u16* d; long off;
    if (i < n0)           { s = s0; d = d0; off = i; }
    else if (i < n0 + n1) { s = s1; d = d1; off = i - n0; }
    else if (i < n0 + n1 + n2) { s = s2; d = d2; off = i - n0 - n1; }
    else return;
    float4 v = *(const float4*)(s + off);
    uint32_t lo = f2bf(v.x) | ((uint32_t)f2bf(v.y) << 16);
    uint32_t hi = f2bf(v.z) | ((uint32_t)f2bf(v.w) << 16);
    *(uint2*)(d + off) = make_uint2(lo, hi);
}

// ---------------------------------------------------------------- embed + token-normalize (fp32, feeds topk)
__global__ __launch_bounds__(256) void embed_k(const int* __restrict__ ids,
                                               const float* __restrict__ wte,
                                               float* __restrict__ x,
                                               float* __restrict__ xnt) {
    __shared__ float sb[4];
    int tok = blockIdx.x;
    const float* src = wte + (size_t)ids[tok] * cE;
    int t = threadIdx.x;
    float v0 = src[t], v1 = src[t + 256], v2 = src[t + 512];
    float tot = blockReduceSum256(v0 * v0 + v1 * v1 + v2 * v2, sb);
    float inv = 1.0f / (sqrtf(tot) + 1e-8f);
    size_t o = (size_t)tok * cE + t;
    x[o] = v0; x[o + 256] = v1; x[o + 512] = v2;
    xnt[o] = v0 * inv; xnt[o + 256] = v1 * inv; xnt[o + 512] = v2 * inv;
}

// ---------------------------------------------------------------- rmsnorm -> bf16
__global__ __launch_bounds__(256) void rmsnorm_bf_k(const float* __restrict__ in,
                                                    const float* __restrict__ w,
                                                    u16* __restrict__ out) {
    __shared__ float sb[4];
    size_t row = blockIdx.x;
    const float* src = in + row * cE;
    int t = threadIdx.x;
    float v0 = src[t], v1 = src[t + 256], v2 = src[t + 512];
    float tot = blockReduceSum256(v0 * v0 + v1 * v1 + v2 * v2, sb);
    float s = 1.0f / sqrtf(tot * (1.0f / cE) + 1e-10f);
    out[row * cE + t]       = f2bf(v0 * s * w[t]);
    out[row * cE + t + 256] = f2bf(v1 * s * w[t + 256]);
    out[row * cE + t + 512] = f2bf(v2 * s * w[t + 512]);
}

// ---------------------------------------------------------------- inverse row norm of a (bf16 input)
__global__ __launch_bounds__(256) void invna_bf_k(const u16* __restrict__ a,
                                                  float* __restrict__ invna) {
    __shared__ float sb[4];
    size_t row = blockIdx.x;
    const u16* src = a + row * cE;
    int t = threadIdx.x;
    float v0 = bf2f(src[t]), v1 = bf2f(src[t + 256]), v2 = bf2f(src[t + 512]);
    float tot = blockReduceSum256(v0 * v0 + v1 * v1 + v2 * v2, sb);
    if (t == 0) invna[row] = 1.0f / sqrtf(tot + 1e-8f);
}

// ---------------------------------------------------------------- final row extract + rmsnorm(lnf) -> bf16
__global__ __launch_bounds__(256) void final_bf_k(const float* __restrict__ h,
                                                  const float* __restrict__ lnf,
                                                  u16* __restrict__ finn) {
    __shared__ float sb[4];
    int tok = blockIdx.x;
    int b = tok >> 11, tt = tok & 2047;
    int i = tt >> 8, c = tt & 255;
    size_t row = (size_t)(b * cN + i) * cTL + (cTL - cC) + c;
    const float* src = h + row * cE;
    int t = threadIdx.x;
    float v0 = src[t], v1 = src[t + 256], v2 = src[t + 512];
    float tot = blockReduceSum256(v0 * v0 + v1 * v1 + v2 * v2, sb);
    float s = 1.0f / sqrtf(tot * (1.0f / cE) + 1e-10f);
    size_t o = (size_t)tok * cE + t;
    finn[o]       = f2bf(v0 * s * lnf[t]);
    finn[o + 256] = f2bf(v1 * s * lnf[t + 256]);
    finn[o + 512] = f2bf(v2 * s * lnf[t + 512]);
}

// ---------------------------------------------------------------- pair scores v2 (fp32, deterministic)
__global__ __launch_bounds__(256) void pair_scores_k(const float* __restrict__ xnt,
                                                     float* __restrict__ partial) {
    __shared__ float As[16][64];
    __shared__ float Bs[4][16][64];
    __shared__ float rowmax[4][64];
    int ct = blockIdx.x;
    int p  = blockIdx.y;
    int b = p / 28, pp = p % 28;
    int i = 1; while (pp >= i) { pp -= i; i++; }
    int j = pp;
    const float* Abase = xnt + ((size_t)(b * cT) + i * cC + ct * 64) * cE;
    const float* Bbase = xnt + ((size_t)(b * cT) + j * cC) * cE;
    int tid = threadIdx.x, lane = tid & 63, w = tid >> 6;
    int ly = lane >> 3, lx = lane & 7;
    int srow = tid >> 2, skc = (tid & 3) << 2;
    const float* bw = Bbase + (size_t)(w * 64) * cE;

    float acc[8][8];
    #pragma unroll
    for (int a2 = 0; a2 < 8; a2++)
        #pragma unroll
        for (int b2 = 0; b2 < 8; b2++) acc[a2][b2] = 0.f;

    for (int k0 = 0; k0 < cE; k0 += 16) {
        float4 va = *(const float4*)(Abase + (size_t)srow * cE + k0 + skc);
        As[skc + 0][srow] = va.x; As[skc + 1][srow] = va.y;
        As[skc + 2][srow] = va.z; As[skc + 3][srow] = va.w;
        #pragma unroll
        for (int q = 0; q < 4; q++) {
            int id = (q << 6) + lane;
            int br = id >> 2, bkc = (id & 3) << 2;
            float4 vb = *(const float4*)(bw + (size_t)br * cE + k0 + bkc);
            Bs[w][bkc + 0][br] = vb.x; Bs[w][bkc + 1][br] = vb.y;
            Bs[w][bkc + 2][br] = vb.z; Bs[w][bkc + 3][br] = vb.w;
        }
        __syncthreads();
        #pragma unroll
        for (int k = 0; k < 16; k++) {
            float av[8], bv[8];
            *(float4*)&av[0] = *(float4*)&As[k][ly << 3];
            *(float4*)&av[4] = *(float4*)&As[k][(ly << 3) + 4];
            *(float4*)&bv[0] = *(float4*)&Bs[w][k][lx << 3];
            *(float4*)&bv[4] = *(float4*)&Bs[w][k][(lx << 3) + 4];
            #pragma unroll
            for (int r = 0; r < 8; r++)
                #pragma unroll
                for (int q = 0; q < 8; q++)
                    acc[r][q] = fmaf(av[r], bv[q], acc[r][q]);
        }
        __syncthreads();
    }
    #pragma unroll
    for (int r = 0; r < 8; r++) {
        float m = acc[r][0];
        #pragma unroll
        for (int q = 1; q < 8; q++) m = fmaxf(m, acc[r][q]);
        m = fmaxf(m, __shfl_xor(m, 1, 64));
        m = fmaxf(m, __shfl_xor(m, 2, 64));
        m = fmaxf(m, __shfl_xor(m, 4, 64));
        if (lx == 0) rowmax[w][(ly << 3) + r] = m;
    }
    __syncthreads();
    if (tid == 0) {
        float s = 0.f;
        for (int r = 0; r < 64; r++)
            s += fmaxf(fmaxf(rowmax[0][r], rowmax[1][r]),
                       fmaxf(rowmax[2][r], rowmax[3][r]));
        partial[p * 4 + ct] = s;
    }
}

// ---------------------------------------------------------------- top-k + sort + weights (unchanged)
__global__ void score_topk_k(const float* __restrict__ partial,
                             int* __restrict__ sidx, float* __restrict__ sw) {
    __shared__ float sc[2][8][8];
    int t = threadIdx.x;
    if (t < 56) {
        int b = t / 28, pp = t % 28;
        int i = 1; while (pp >= i) { pp -= i; i++; }
        int j = pp;
        sc[b][i][j] = partial[t * 4 + 0] + partial[t * 4 + 1] + partial[t * 4 + 2] + partial[t * 4 + 3];
    }
    __syncthreads();
    if (t < 16) {
        int b = t >> 3, i = t & 7;
        int nsel = i < 3 ? i : 3;
        if (nsel > 0) {
            float loc[7];
            for (int j2 = 0; j2 < i; j2++) loc[j2] = sc[b][i][j2];
            int idxs[3]; float vals[3];
            for (int s = 0; s < nsel; s++) {
                int am = 0; float mv = loc[0];
                for (int j2 = 1; j2 < i; j2++) if (loc[j2] > mv) { mv = loc[j2]; am = j2; }
                idxs[s] = am; vals[s] = mv; loc[am] = -1e30f;
            }
            for (int a = 0; a < nsel; a++)
                for (int c2 = a + 1; c2 < nsel; c2++)
                    if (idxs[c2] < idxs[a]) {
                        int ti = idxs[a]; idxs[a] = idxs[c2]; idxs[c2] = ti;
                        float tv = vals[a]; vals[a] = vals[c2]; vals[c2] = tv;
                    }
            float den = vals[0] + 1e-8f;
            for (int s = 0; s < nsel; s++) {
                sidx[(b * 8 + i) * 3 + s] = idxs[s];
                sw[(b * 8 + i) * 3 + s]   = vals[s] / den;
            }
        }
    }
}

// ---------------------------------------------------------------- assemble extended context h (fp32)
__global__ __launch_bounds__(192) void build_k(const float* __restrict__ x,
                                               const int* __restrict__ sidx,
                                               const float* __restrict__ sw,
                                               float* __restrict__ h) {
    int m = blockIdx.x, r = blockIdx.y;
    int b = m >> 3, i = m & 7;
    int nsel = i < 3 ? i : 3;
    int pad = cTL - (nsel + 1) * cC;
    int pos = r - pad;
    float4 val = make_float4(0.f, 0.f, 0.f, 0.f);
    if (pos >= 0) {
        if (pos < nsel * cC) {
            int s = pos >> 8;
            int jj = sidx[(b * 8 + i) * 3 + s];
            float wg = sw[(b * 8 + i) * 3 + s];
            const float4* src = (const float4*)(x + ((size_t)(b * cT) + jj * cC + (pos & 255)) * cE);
            float4 v = src[threadIdx.x];
            val = make_float4(v.x * wg, v.y * wg, v.z * wg, v.w * wg);
        } else {
            int c = pos - nsel * cC;
            const float4* src = (const float4*)(x + ((size_t)(b * cT) + i * cC + c) * cE);
            val = src[threadIdx.x];
        }
    }
    ((float4*)(h + ((size_t)m * cTL + r) * cE))[threadIdx.x] = val;
}

enum { GE_F32 = 0, GE_RELU = 1, GE_CS = 2, GE_ADDH = 3, GE_ANBT = 4 };

// ---------------------------------------------------------------- 256x256 pipelined MFMA GEMM v3
// NT: C[m,n] = sum_k A[m*lda+k]*B[n*ldb+k]. BK=32, ring-4 LDS (4x32KB), 8 waves (2Mx4N).
// Per iteration: {12 ds_read | stage tile t+3 (4 gloads) | vmcnt(8) | 1 barrier | 32 MFMA}.
// Hazard proof: barrier(t) collective => all waves done reading slot t&3 before any wave's
// stage(t+4) (issued after barrier(t)) can write that slot. Tile t+1 landed via vmcnt(8)+bar.
template <int EPI>
__global__ __launch_bounds__(512, 2) void gemm256(
        const u16* __restrict__ A, int lda,
        const u16* __restrict__ B, int ldb,
        void* __restrict__ Cv, int ldc, int K,
        const float* __restrict__ bias,
        u16* __restrict__ p0, u16* __restrict__ p1, u16* __restrict__ p2,
        int swz)
{
    __shared__ __align__(16) u16 lds[65536];   // 4 slots x 16384 u16 (A:8192, B:8192)
    int bx = blockIdx.x, by = blockIdx.y;
    if (swz == 3) {   // XCD owns gy/8 m-tiles; all XCDs sweep n in sync
        int gx = gridDim.x, gy = gridDim.y;
        int orig = by * gx + bx;
        int mpx = gy >> 3;
        int xcd = orig & 7, idx = orig >> 3;
        by = xcd * mpx + idx % mpx;
        bx = idx / mpx;
        (void)gx;
    }
    const int n0 = bx << 8, m0 = by << 8;
    const int tid = threadIdx.x, lane = tid & 63, w = tid >> 6;
    const int wm = w >> 2, wn = w & 3;

    const u16* Ab = A + (size_t)m0 * lda;
    const u16* Bb = B + (size_t)n0 * ldb;

    // staging: thread tid owns LDS 16B chunk tid within each 8KB round
    const int srow = tid >> 2;                         // rows 0..127 (+128 in round 2)
    const int sq   = (tid & 3) ^ ((srow >> 1) & 3);    // pre-swizzled global 16B-chunk
    u16* ldst = lds + (size_t)tid * 8;

    f32x4 acc[8][4];
    #pragma unroll
    for (int m = 0; m < 8; m++)
        #pragma unroll
        for (int n = 0; n < 4; n++) acc[m][n] = (f32x4){0.f, 0.f, 0.f, 0.f};

    const int NT = K >> 5;

    auto STAGE_A = [&](int tt) {
        const u16* src = Ab + (size_t)tt * 32 + (size_t)sq * 8;
        u16* d = ldst + ((tt & 3) << 14);
        GLOAD16(src + (size_t)srow * lda,         d);
        GLOAD16(src + (size_t)(srow + 128) * lda, d + 4096);
    };
    auto STAGE_B = [&](int tt) {
        const u16* src = Bb + (size_t)tt * 32 + (size_t)sq * 8;
        u16* d = ldst + ((tt & 3) << 14) + 8192;
        GLOAD16(src + (size_t)srow * ldb,         d);
        GLOAD16(src + (size_t)(srow + 128) * ldb, d + 4096);
    };

    const int l15 = lane & 15;
    const int ck  = (((lane >> 4) ^ ((l15 >> 1) & 3)) << 3);   // u16 offset within row

    // prologue: stage tiles 0,1,2; ensure tile 0 landed (8 newest may remain in flight)
    STAGE_A(0); STAGE_B(0);
    STAGE_A(1); STAGE_B(1);
    STAGE_A(2); STAGE_B(2);
    asm volatile("s_waitcnt vmcnt(8)" ::: "memory");
    __builtin_amdgcn_s_barrier();

    for (int t = 0; t < NT; ++t) {
        const u16* S  = lds + ((t & 3) << 14);
        const u16* SB = S + 8192;
        bf16x8 bfr[4], af[8];
        #pragma unroll
        for (int nf = 0; nf < 4; nf++)
            bfr[nf] = *(const bf16x8*)(SB + (size_t)((wn << 6) + (nf << 4) + l15) * 32 + ck);
        #pragma unroll
        for (int i = 0; i < 8; i++)
            af[i] = *(const bf16x8*)(S + (size_t)((wm << 7) + (i << 4) + l15) * 32 + ck);
        if (t + 3 < NT) { STAGE_A(t + 3); STAGE_B(t + 3); }
        if (t + 3 < NT)      asm volatile("s_waitcnt vmcnt(8)" ::: "memory");
        else if (t + 2 < NT) asm volatile("s_waitcnt vmcnt(4)" ::: "memory");
        else                 asm volatile("s_waitcnt vmcnt(0)" ::: "memory");
        __builtin_amdgcn_s_barrier();
        __builtin_amdgcn_s_setprio(1);
        #pragma unroll
        for (int i = 0; i < 8; i++)
            #pragma unroll
            for (int nf = 0; nf < 4; nf++)
                acc[i][nf] = __builtin_amdgcn_mfma_f32_16x16x32_bf16(af[i], bfr[nf], acc[i][nf], 0, 0, 0);
        __builtin_amdgcn_s_setprio(0);
    }

    // epilogue: C/D layout col=lane&15, row=(lane>>4)*4+j
    const int r0 = (lane >> 4) << 2;
    const int c0 = lane & 15;

    if constexpr (EPI == GE_F32) {
        float* Cb = (float*)Cv;
        #pragma unroll
        for (int mf = 0; mf < 8; mf++) {
            int gmb = m0 + (wm << 7) + (mf << 4) + r0;
            #pragma unroll
            for (int j = 0; j < 4; j++) {
                float* crow = Cb + (size_t)(gmb + j) * ldc;
                #pragma unroll
                for (int nf = 0; nf < 4; nf++)
                    crow[n0 + (wn << 6) + (nf << 4) + c0] = acc[mf][nf][j];
            }
        }
    } else if constexpr (EPI == GE_ADDH) {
        float* Cb = (float*)Cv;
        #pragma unroll
        for (int mf = 0; mf < 8; mf++) {
            int gmb = m0 + (wm << 7) + (mf << 4) + r0;
            #pragma unroll
            for (int j = 0; j < 4; j++) {
                float* crow = Cb + (size_t)(gmb + j) * ldc;
                #pragma unroll
                for (int nf = 0; nf < 4; nf++) {
                    int gn = n0 + (wn << 6) + (nf << 4) + c0;
                    crow[gn] = crow[gn] + acc[mf][nf][j] + bias[gn];
                }
            }
        }
    } else if constexpr (EPI == GE_RELU) {
        const bool aregion = (n0 < cE);
        #pragma unroll
        for (int mf = 0; mf < 8; mf++) {
            const int gmb = m0 + (wm << 7) + (mf << 4) + r0;
            const int zz = gmb >> 10, cm = gmb & 1023;
            #pragma unroll
            for (int nf = 0; nf < 4; nf++) {
                const int gn = n0 + (wn << 6) + (nf << 4) + c0;
                const float bv = bias[gn];
                u16 rb[4];
                #pragma unroll
                for (int j = 0; j < 4; j++) {
                    float tv = acc[mf][nf][j] + bv;
                    tv = fmaxf(tv, 0.f);
                    rb[j] = f2bf(tv * tv);
                }
                if (aregion) {
                    #pragma unroll
                    for (int j = 0; j < 4; j++)
                        p0[(size_t)(gmb + j) * cE + gn] = rb[j];
                    uint32_t lo = rb[0] | ((uint32_t)rb[1] << 16);
                    uint32_t hi = rb[2] | ((uint32_t)rb[3] << 16);
                    *(uint2*)&p1[(size_t)zz * (cE * cTL) + (size_t)gn * cTL + cm] = make_uint2(lo, hi);
                } else {
                    #pragma unroll
                    for (int j = 0; j < 4; j++)
                        p2[(size_t)(gmb + j) * cPIN + (gn - cE)] = rb[j];
                }
            }
        }
    }
}

// ---------------------------------------------------------------- bf16 MFMA GEMM (128x128) for cs / a_newT(+fused tmul)
template <int EPI>
__global__ __launch_bounds__(256) void gemm_bt(
        const u16* __restrict__ A, int lda, size_t sA,
        const u16* __restrict__ B, int ldb, size_t sB,
        void* __restrict__ Cv, int ldc, size_t sC, int K,
        const float* __restrict__ invn,
        const float* __restrict__ sp,
        int kcap,
        u16* __restrict__ fiout)
{
    const int n0 = blockIdx.x << 7, m0 = blockIdx.y << 7, z = blockIdx.z;
    const int tid = threadIdx.x, lane = tid & 63, w = tid >> 6;
    const int wr = w >> 1, wc = w & 1;

    if constexpr (EPI == GE_CS) {
        if (n0 > m0) return;   // strictly-upper blocks never read downstream (K-capped consumer)
    }

    const int Keff = kcap ? ((K < n0 + 128) ? K : n0 + 128) : K;

    __shared__ __align__(16) u16 As[128 * 32];
    __shared__ __align__(16) u16 Bs[128 * 32];

    const u16* Ab = A + (size_t)z * sA + (size_t)m0 * lda;
    const u16* Bb = B + (size_t)z * sB + (size_t)n0 * ldb;

    const int srow = (w << 5) + (lane >> 2);
    const int skof = (lane & 3) << 3;
    const u16* ga0 = Ab + (size_t)srow * lda + skof;
    const u16* gb0 = Bb + (size_t)srow * ldb + skof;
    u16* la0 = As + (w << 10);
    u16* lb0 = Bs + (w << 10);

    f32x4 acc[4][4];
    #pragma unroll
    for (int m = 0; m < 4; m++)
        #pragma unroll
        for (int n = 0; n < 4; n++)
            acc[m][n] = (f32x4){0.f, 0.f, 0.f, 0.f};

    const int arow = (wr << 6) + (lane & 15);
    const int brow = (wc << 6) + (lane & 15);
    const int koff = (lane >> 4) << 3;

    for (int kt = 0; kt < Keff; kt += 32) {
        GLOAD16(ga0 + kt, la0);
        GLOAD16(ga0 + kt + (size_t)16 * lda, la0 + 512);
        GLOAD16(gb0 + kt, lb0);
        GLOAD16(gb0 + kt + (size_t)16 * ldb, lb0 + 512);
        __syncthreads();
        bf16x8 af[4], bfr[4];
        #pragma unroll
        for (int m = 0; m < 4; m++)
            af[m] = *(const bf16x8*)&As[(arow + (m << 4)) * 32 + koff];
        #pragma unroll
        for (int n = 0; n < 4; n++)
            bfr[n] = *(const bf16x8*)&Bs[(brow + (n << 4)) * 32 + koff];
        #pragma unroll
        for (int m = 0; m < 4; m++)
            #pragma unroll
            for (int n = 0; n < 4; n++)
                acc[m][n] = __builtin_amdgcn_mfma_f32_16x16x32_bf16(af[m], bfr[n], acc[m][n], 0, 0, 0);
        __syncthreads();
    }

    const int r0 = (lane >> 4) << 2;
    const int c0 = lane & 15;

    if constexpr (EPI == GE_ANBT) {
        // acc = a_newT tile: e = m0+..., m = n0+...  Fused: fi[z*TL+m][e] *= a_new[m][e]
        __shared__ u16 tr[128][129];
        #pragma unroll
        for (int m = 0; m < 4; m++) {
            int el = (wr << 6) + (m << 4) + r0;
            #pragma unroll
            for (int j = 0; j < 4; j++)
                #pragma unroll
                for (int n = 0; n < 4; n++)
                    tr[el + j][(wc << 6) + (n << 4) + c0] = f2bf(acc[m][n][j]);
        }
        __syncthreads();
        const int mrow = tid >> 1, e0h = (tid & 1) << 6;
        u16* fr = fiout + ((size_t)(z * cTL + n0 + mrow)) * cPIN + m0 + e0h;
        #pragma unroll
        for (int ee = 0; ee < 64; ee += 8) {
            uint4 fv = *(uint4*)(fr + ee);
            u16* pf = (u16*)&fv;
            u16 res[8];
            #pragma unroll
            for (int q = 0; q < 8; q++)
                res[q] = f2bf(bf2f(tr[e0h + ee + q][mrow]) * bf2f(pf[q]));
            *(uint4*)(fr + ee) = *(uint4*)res;
        }
    } else if constexpr (EPI == GE_CS) {
        u16* Cb = (u16*)Cv + (size_t)z * sC;
        const float* invz = invn + (z << 10);
        float inn[4];
        #pragma unroll
        for (int n = 0; n < 4; n++)
            inn[n] = invz[n0 + (wc << 6) + (n << 4) + c0];
        #pragma unroll
        for (int m = 0; m < 4; m++) {
            int gmb = m0 + (wr << 6) + (m << 4) + r0;
            #pragma unroll
            for (int j = 0; j < 4; j++) {
                int gm = gmb + j;
                float im = invz[gm];
                const float* spr = sp + (size_t)gm * cTL;
                u16* crow = Cb + (size_t)gm * ldc;
                #pragma unroll
                for (int n = 0; n < 4; n++) {
                    int gn = n0 + (wc << 6) + (n << 4) + c0;
                    float v = (gn <= gm) ? acc[m][n][j] * im * inn[n] * spr[gn] : 0.f;
                    crow[gn] = f2bf(v);
                }
            }
        }
    }
}

// ---------------------------------------------------------------- launch
extern "C" void kernel_launch(void* const* d_in, const int* in_sizes, int n_in,
                              void* d_out, int out_size, void* d_ws, size_t ws_size,
                              hipStream_t stream) {
    const int*   ids  = (const int*)d_in[0];
    const float* wte  = (const float*)d_in[1];
    const float* rmsw = (const float*)d_in[2];
    const float* enrw = (const float*)d_in[3];
    const float* enrb = (const float*)d_in[4];
    const float* sp   = (const float*)d_in[5];
    const float* fusw = (const float*)d_in[6];
    const float* fusb = (const float*)d_in[7];
    const float* lnfw = (const float*)d_in[8];
    float* out = (float*)d_out;

    // fp32 workspace
    float* ws   = (float*)d_ws;
    float* x    = ws;                      // 3,145,728
    float* xnt  = x    + 3145728;          // 3,145,728
    float* h    = xnt  + 3145728;          // 12,582,912
    float* invn = h    + 12582912;         // 16,384
    float* part = invn + 16384;            // 256
    float* swv  = part + 256;              // 64
    int*   sidx = (int*)(swv + 64);        // 64
    // bf16 workspace
    u16* wteb  = (u16*)(sidx + 64);        // 24,576,000
    u16* enrwb = wteb  + 24576000;         //  9,437,184
    u16* fuswb = enrwb + 9437184;          //  7,077,888
    u16* xnb   = fuswb + 7077888;          // 12,582,912 (reused as finn bf16)
    u16* abuf  = xnb   + 12582912;         // 12,582,912
    u16* aTb   = abuf  + 12582912;         // 12,582,912
    u16* fi    = aTb   + 12582912;         // 37,748,736
    u16* csb   = fi    + 37748736;         // 16,777,216
    u16* finnb = xnb;

    // 0. weight conversion fp32->bf16 (single launch)
    cvt3_k<<<(24576000 + 9437184 + 7077888) / 1024, 256, 0, stream>>>(
        wte, wteb, 24576000, enrw, enrwb, 9437184, fusw, fuswb, 7077888);

    // 1. embed + token normalize (fp32)
    embed_k<<<cB * cT, 256, 0, stream>>>(ids, wte, x, xnt);
    // 2. retrieval scores + top-k + assembly (fp32, deterministic)
    pair_scores_k<<<dim3(4, 56), 256, 0, stream>>>(xnt, part);
    score_topk_k<<<1, 64, 0, stream>>>(part, sidx, swv);
    build_k<<<dim3(cNCH, cTL), 192, 0, stream>>>(x, sidx, swv, h);

    // 3. layers
    for (int l = 0; l < cL; l++) {
        rmsnorm_bf_k<<<cMR, 256, 0, stream>>>(h, rmsw + (size_t)l * cE, xnb);
        // xp = relu(xn @ enr_w.T + b)^2 ; writes a (row-major + transposed) and b/x1 into fi
        gemm256<GE_RELU><<<dim3(cED / 256, cMR / 256), 512, 0, stream>>>(
            xnb, cE, enrwb + (size_t)l * cED * cE, cE,
            nullptr, 0, cE, enrb + (size_t)l * cED,
            abuf, aTb, fi, 3);
        invna_bf_k<<<cMR, 256, 0, stream>>>(abuf, invn);
        // M = tril(sp) * cosine(a,a)
        gemm_bt<GE_CS><<<dim3(8, 8, cNCH), 256, 0, stream>>>(
            abuf, cE, (size_t)cTL * cE, abuf, cE, (size_t)cTL * cE,
            csb, cTL, (size_t)cTL * cTL, cE,
            invn, sp + (size_t)l * cTL * cTL, 0, nullptr);
        // a_newT[e][m] = sum_c aT[e][c]*M[m][c] (K capped at n0+128); fused fi[m][e] *= result
        gemm_bt<GE_ANBT><<<dim3(8, 6, cNCH), 256, 0, stream>>>(
            aTb, cTL, (size_t)cE * cTL, csb, cTL, (size_t)cTL * cTL,
            nullptr, 0, 0, cTL,
            nullptr, nullptr, 1, fi);
        // h += fi @ fus_w.T + fus_b
        gemm256<GE_ADDH><<<dim3(cE / 256, cMR / 256), 512, 0, stream>>>(
            fi, cPIN, fuswb + (size_t)l * cE * cPIN, cPIN,
            h, cE, cPIN, fusb + (size_t)l * cE,
            nullptr, nullptr, nullptr, 3);
    }

    // 4. final norm + logits
    final_bf_k<<<cB * cT, 256, 0, stream>>>(h, lnfw, finnb);
    gemm256<GE_F32><<<dim3(cV / 256, (cB * cT) / 256), 512, 0, stream>>>(
        finnb, cE, wteb, cE, out, cV, cE,
        nullptr, nullptr, nullptr, nullptr, 3);
}